// Round 1
// baseline (161.474 us; speedup 1.0000x reference)
//
#include <hip/hip_runtime.h>

// Le-ADMM reduction: every iteration resets ADMM state to zero, so the output
// is a single linear filter applied to pad(x):
//   out = crop_shift( IFFT2( K . FFT2(pad(x)) ) )
//   K(k,l) = mu1[4]/((1+1e-6)*FH*FW) * conj(Hp(k,l)) * R_div(k,l)
//   Hp = FFT2(pad(h)) (plain), R_div = 1/(1e-6|Hp|^2 + 1e-5*PsiTPsi + 4e-5)
//   PsiTPsi = 4 - 2cos(2pi k/FH) - 2cos(2pi l/FW)
// All fft/ifftshifts fold into (-1)^{k+l} factors that cancel except one
// residual output shift handled by index remap at crop time.
// Images are processed in pairs z = x_a + i*x_b (K Hermitian => both results
// real, recovered as Re/Im).

#define FH 1080
#define FW 1920
#define SH 540
#define SW 960

__device__ __forceinline__ float2 cadd(float2 a, float2 b){ return make_float2(a.x+b.x, a.y+b.y); }
__device__ __forceinline__ float2 csub(float2 a, float2 b){ return make_float2(a.x-b.x, a.y-b.y); }
__device__ __forceinline__ float2 cmul(float2 a, float2 b){ return make_float2(a.x*b.x - a.y*b.y, a.x*b.y + a.y*b.x); }

// LDS pad swizzle: +1 element every 16 to break stride-16 bank conflicts in
// Stockham write patterns.
__device__ __forceinline__ int IDX(int a){ return a + (a >> 4); }
#define IDXSZ(n) ((n) + ((n) >> 4))

// One Stockham stage. NCUR = current sub-transform length, S = stride
// (= batch * product of done radices). Data: src[q + S*(p + (NCUR/R)*t)].
template<int DIR, int R, int NCUR, int S>
__device__ __forceinline__ void do_stage(const float2* __restrict__ src,
                                         float2* __restrict__ dst,
                                         int tid, int nthr)
{
    constexpr int M  = NCUR / R;
    constexpr int NB = M * S;
    constexpr float STEP = (float)DIR * 6.2831853071795864f / (float)NCUR;
    for (int i = tid; i < NB; i += nthr) {
        const int p = i / S;           // S compile-time -> cheap
        float2 a0, a1, a2, a3, a4;
        a0 = src[IDX(i)];
        a1 = src[IDX(i + S*M)];
        if constexpr (R >= 3) a2 = src[IDX(i + 2*S*M)];
        if constexpr (R >= 4) a3 = src[IDX(i + 3*S*M)];
        if constexpr (R >= 5) a4 = src[IDX(i + 4*S*M)];

        float2 b0, b1, b2, b3, b4;
        if constexpr (R == 2) {
            b0 = cadd(a0, a1); b1 = csub(a0, a1);
        } else if constexpr (R == 3) {
            constexpr float s3 = (float)DIR * 0.8660254037844386f;
            float2 t = cadd(a1, a2), u = csub(a1, a2);
            float2 mm = make_float2(a0.x - 0.5f*t.x, a0.y - 0.5f*t.y);
            float2 iu = make_float2(-s3*u.y, s3*u.x);
            b0 = cadd(a0, t); b1 = cadd(mm, iu); b2 = csub(mm, iu);
        } else if constexpr (R == 4) {
            float2 t0 = cadd(a0,a2), t1 = csub(a0,a2), t2 = cadd(a1,a3), t3 = csub(a1,a3);
            float2 j3 = make_float2(-(float)DIR*t3.y, (float)DIR*t3.x);
            b0 = cadd(t0,t2); b2 = csub(t0,t2); b1 = cadd(t1,j3); b3 = csub(t1,j3);
        } else { // R == 5
            constexpr float C1 = 0.30901699437494742f, S1c = 0.9510565162951535f;
            constexpr float C2 = -0.8090169943749475f, S2c = 0.5877852522924731f;
            float2 t1 = cadd(a1,a4), t2 = cadd(a2,a3), d1 = csub(a1,a4), d2 = csub(a2,a3);
            float2 m1 = make_float2(a0.x + C1*t1.x + C2*t2.x, a0.y + C1*t1.y + C2*t2.y);
            float2 m2 = make_float2(a0.x + C2*t1.x + C1*t2.x, a0.y + C2*t1.y + C1*t2.y);
            float2 e1 = make_float2(S1c*d1.x + S2c*d2.x, S1c*d1.y + S2c*d2.y);
            float2 e2 = make_float2(S2c*d1.x - S1c*d2.x, S2c*d1.y - S1c*d2.y);
            float2 ie1 = make_float2(-(float)DIR*e1.y, (float)DIR*e1.x);
            float2 ie2 = make_float2(-(float)DIR*e2.y, (float)DIR*e2.x);
            b0 = make_float2(a0.x + t1.x + t2.x, a0.y + t1.y + t2.y);
            b1 = cadd(m1, ie1); b4 = csub(m1, ie1);
            b2 = cadd(m2, ie2); b3 = csub(m2, ie2);
        }

        // twiddle: b_u *= exp(DIR*2pi*i*p*u/NCUR)
        float sv, cv;
        __sincosf(STEP * (float)p, &sv, &cv);
        float2 w1 = make_float2(cv, sv);
        b1 = cmul(b1, w1);
        if constexpr (R >= 3) {
            float2 w2 = cmul(w1, w1); b2 = cmul(b2, w2);
            if constexpr (R >= 4) { float2 w3 = cmul(w2, w1); b3 = cmul(b3, w3); }
            if constexpr (R >= 5) { float2 w4 = cmul(w2, w2); b4 = cmul(b4, w4); }
        }

        const int ob = (i - p*S) + S*(R*p);   // q + S*R*p
        dst[IDX(ob)]       = b0;
        dst[IDX(ob + S)]   = b1;
        if constexpr (R >= 3) dst[IDX(ob + 2*S)] = b2;
        if constexpr (R >= 4) dst[IDX(ob + 3*S)] = b3;
        if constexpr (R >= 5) dst[IDX(ob + 4*S)] = b4;
    }
}

// 1920 = 4*4*4*2*3*5 : 6 stages, result ends in bA (natural order).
template<int DIR, int B>
__device__ __forceinline__ void fft1920(float2* bA, float2* bB, int tid, int nthr){
    do_stage<DIR,4,1920,    B>(bA,bB,tid,nthr); __syncthreads();
    do_stage<DIR,4, 480,  4*B>(bB,bA,tid,nthr); __syncthreads();
    do_stage<DIR,4, 120, 16*B>(bA,bB,tid,nthr); __syncthreads();
    do_stage<DIR,2,  30, 64*B>(bB,bA,tid,nthr); __syncthreads();
    do_stage<DIR,3,  15,128*B>(bA,bB,tid,nthr); __syncthreads();
    do_stage<DIR,5,   5,384*B>(bB,bA,tid,nthr); __syncthreads();
}

// 1080 = 4*3*3*3*2*5 : 6 stages, result ends in bA.
template<int DIR, int B>
__device__ __forceinline__ void fft1080(float2* bA, float2* bB, int tid, int nthr){
    do_stage<DIR,4,1080,    B>(bA,bB,tid,nthr); __syncthreads();
    do_stage<DIR,3, 270,  4*B>(bB,bA,tid,nthr); __syncthreads();
    do_stage<DIR,3,  90, 12*B>(bA,bB,tid,nthr); __syncthreads();
    do_stage<DIR,3,  30, 36*B>(bB,bA,tid,nthr); __syncthreads();
    do_stage<DIR,2,  10,108*B>(bA,bB,tid,nthr); __syncthreads();
    do_stage<DIR,5,   5,216*B>(bB,bA,tid,nthr); __syncthreads();
}

// K1: row FFTs of padded h (only the 540 nonzero rows). Hrow[r][k], r=0..539
// maps to padded row 270+r.
__global__ __launch_bounds__(256) void k_row_fft_h(const float* __restrict__ h,
                                                   float2* __restrict__ Hrow)
{
    __shared__ float2 bA[IDXSZ(1920)], bB[IDXSZ(1920)];
    const int tid = threadIdx.x;
    const int r = blockIdx.x;
    for (int i = tid; i < 1920; i += 256) {
        float2 v = make_float2(0.f, 0.f);
        if (i >= 480 && i < 1440) v.x = h[r*960 + (i - 480)];
        bA[IDX(i)] = v;
    }
    __syncthreads();
    fft1920<-1,1>(bA, bB, tid, 256);
    for (int i = tid; i < 1920; i += 256) Hrow[r*1920 + i] = bA[IDX(i)];
}

// K2: column FFTs of Hrow (4 columns per block, batched Stockham s0=4),
// then build K transposed: KT[c][k].
__global__ __launch_bounds__(256) void k_col_fft_h_buildK(const float2* __restrict__ Hrow,
                                                          const float* __restrict__ mu1,
                                                          float2* __restrict__ KT)
{
    __shared__ float2 bA[IDXSZ(4320)], bB[IDXSZ(4320)];
    const int tid = threadIdx.x;
    const int c0 = blockIdx.x * 4;
    for (int i = tid; i < 4320; i += 256) {
        int k = i >> 2, cc = i & 3;
        float2 v = make_float2(0.f, 0.f);
        if (k >= 270 && k < 810) v = Hrow[(k - 270)*1920 + c0 + cc];
        bA[IDX(i)] = v;
    }
    __syncthreads();
    fft1080<-1,4>(bA, bB, tid, 256);
    const float sc = mu1[4] / ((1.0f + 1e-6f) * 2073600.0f); // /(1+mu1_0)/ (FH*FW)
    for (int i = tid; i < 4320; i += 256) {
        int k = i >> 2, c = c0 + (i & 3);
        float2 Hv = bA[IDX(i)];
        float mag2 = Hv.x*Hv.x + Hv.y*Hv.y;
        float ps = 4.0f - 2.0f*__cosf(6.2831853071795864f * (float)k * (1.0f/1080.0f))
                        - 2.0f*__cosf(6.2831853071795864f * (float)c * (1.0f/1920.0f));
        float rdiv = 1.0f / (1e-6f*mag2 + 1e-5f*ps + 4e-5f);
        float f = sc * rdiv;
        KT[c*1080 + k] = make_float2(f*Hv.x, -f*Hv.y);   // conj(Hp) * scale
    }
}

// K3: row FFTs of padded x, two images packed as z = x_a + i*x_b.
// Z[p][r][k], r=0..539 maps to padded row 270+r.
__global__ __launch_bounds__(256) void k_row_fft_x(const float* __restrict__ x,
                                                   float2* __restrict__ Z)
{
    __shared__ float2 bA[IDXSZ(1920)], bB[IDXSZ(1920)];
    const int tid = threadIdx.x;
    const int p = blockIdx.x / 540;
    const int r = blockIdx.x % 540;
    const float* xa = x + ((2*p    )*540 + r)*960;
    const float* xb = x + ((2*p + 1)*540 + r)*960;
    for (int i = tid; i < 1920; i += 256) {
        float2 v = make_float2(0.f, 0.f);
        if (i >= 480 && i < 1440) { v.x = xa[i - 480]; v.y = xb[i - 480]; }
        bA[IDX(i)] = v;
    }
    __syncthreads();
    fft1920<-1,1>(bA, bB, tid, 256);
    float2* Zp = Z + (p*540 + r)*1920;
    for (int i = tid; i < 1920; i += 256) Zp[i] = bA[IDX(i)];
}

// K4: fused column pass: FFT(1080) -> *K -> IFFT(1080), 4 columns per block,
// in-place on Z (block owns its columns). Only the 540 rows needed by the
// final crop are written back; row index remap (i+810)%1080 folded in here.
__global__ __launch_bounds__(256) void k_col_fused(float2* __restrict__ Z,
                                                   const float2* __restrict__ KT)
{
    __shared__ float2 bA[IDXSZ(4320)], bB[IDXSZ(4320)];
    const int tid = threadIdx.x;
    const int p  = blockIdx.x / 480;
    const int c0 = (blockIdx.x % 480) * 4;
    float2* Zp = Z + p*540*1920;
    for (int i = tid; i < 4320; i += 256) {
        int k = i >> 2, cc = i & 3;
        float2 v = make_float2(0.f, 0.f);
        if (k >= 270 && k < 810) v = Zp[(k - 270)*1920 + c0 + cc];
        bA[IDX(i)] = v;
    }
    __syncthreads();
    fft1080<-1,4>(bA, bB, tid, 256);
    for (int i = tid; i < 4320; i += 256) {
        int k = i >> 2, c = c0 + (i & 3);
        bA[IDX(i)] = cmul(bA[IDX(i)], KT[c*1080 + k]);
    }
    __syncthreads();
    fft1080<1,4>(bA, bB, tid, 256);
    for (int i = tid; i < 540*4; i += 256) {
        int ir = i >> 2, cc = i & 3;
        int src = (ir < 270) ? (ir + 810) : (ir - 270);   // (ir+810) mod 1080
        Zp[ir*1920 + c0 + cc] = bA[IDX(4*src + cc)];
    }
}

// K5: row IFFTs + column crop remap (j+1440)%1920 + split pair into the two
// real output images.
__global__ __launch_bounds__(256) void k_row_ifft_out(const float2* __restrict__ Z,
                                                      float* __restrict__ out)
{
    __shared__ float2 bA[IDXSZ(1920)], bB[IDXSZ(1920)];
    const int tid = threadIdx.x;
    const int p = blockIdx.x / 540;
    const int r = blockIdx.x % 540;
    const float2* Zp = Z + (p*540 + r)*1920;
    for (int i = tid; i < 1920; i += 256) bA[IDX(i)] = Zp[i];
    __syncthreads();
    fft1920<1,1>(bA, bB, tid, 256);
    float* oa = out + ((2*p    )*540 + r)*960;
    float* ob = out + ((2*p + 1)*540 + r)*960;
    for (int j = tid; j < 960; j += 256) {
        int src = (j < 480) ? (j + 1440) : (j - 480);     // (j+1440) mod 1920
        float2 v = bA[IDX(src)];
        oa[j] = v.x;
        ob[j] = v.y;
    }
}

extern "C" void kernel_launch(void* const* d_in, const int* in_sizes, int n_in,
                              void* d_out, int out_size, void* d_ws, size_t ws_size,
                              hipStream_t stream)
{
    (void)in_sizes; (void)n_in; (void)out_size; (void)ws_size;
    const float* x   = (const float*)d_in[0];
    const float* h   = (const float*)d_in[1];
    const float* mu1 = (const float*)d_in[2];
    float*       out = (float*)d_out;

    // ws layout: KT (1080*1920 c64 = 16.6MB) | Z (4*540*1920 c64 = 33.2MB)
    // Hrow (540*1920) aliases the Z region (consumed before Z is written).
    float2* KT   = (float2*)d_ws;
    float2* Z    = KT + 1080*1920;
    float2* Hrow = Z;

    k_row_fft_h      <<<540,     256, 0, stream>>>(h, Hrow);
    k_col_fft_h_buildK<<<480,    256, 0, stream>>>(Hrow, mu1, KT);
    k_row_fft_x      <<<4*540,   256, 0, stream>>>(x, Z);
    k_col_fused      <<<4*480,   256, 0, stream>>>(Z, KT);
    k_row_ifft_out   <<<4*540,   256, 0, stream>>>(Z, out);
}

// Round 2
// 150.907 us; speedup vs baseline: 1.0700x; 1.0700x over previous
//
#include <hip/hip_runtime.h>

// Le-ADMM reduction: every iteration resets ADMM state to zero, so the output
// is a single linear filter applied to pad(x):
//   out = crop_shift( IFFT2( K . FFT2(pad(x)) ) )
//   K(k,l) = mu1[4]/((1+1e-6)*FH*FW) * conj(Hp(k,l)) * R_div(k,l)
// Images processed in pairs z = x_a + i*x_b (K Hermitian => results real).
//
// R1 changes: col kernels B=4->2 cols/block (LDS 73.7->36.7KB, 2->4 blocks/CU);
// forward stage-1 reads global directly with zero-pad specialization (a0=a3=0);
// K-multiply fused into inverse stage-1; row kernels stage-1 direct from
// global; launch_bounds (256,5) on row kernels (5 blocks/CU).

#define PI2 6.2831853071795864f

__device__ __forceinline__ float2 cadd(float2 a, float2 b){ return make_float2(a.x+b.x, a.y+b.y); }
__device__ __forceinline__ float2 csub(float2 a, float2 b){ return make_float2(a.x-b.x, a.y-b.y); }
__device__ __forceinline__ float2 cmul(float2 a, float2 b){ return make_float2(a.x*b.x - a.y*b.y, a.x*b.y + a.y*b.x); }

// LDS pad: +1 element every 16 to break stride-16 bank conflicts.
__device__ __forceinline__ int IDX(int a){ return a + (a >> 4); }
#define IDXSZ(n) ((n) + ((n) >> 4))

// One Stockham stage. NCUR = current sub-transform length, S = stride.
template<int DIR, int R, int NCUR, int S>
__device__ __forceinline__ void do_stage(const float2* __restrict__ src,
                                         float2* __restrict__ dst,
                                         int tid, int nthr)
{
    constexpr int M  = NCUR / R;
    constexpr int NB = M * S;
    constexpr float STEP = (float)DIR * PI2 / (float)NCUR;
    for (int i = tid; i < NB; i += nthr) {
        const int p = i / S;
        float2 a0, a1, a2, a3, a4;
        a0 = src[IDX(i)];
        a1 = src[IDX(i + S*M)];
        if constexpr (R >= 3) a2 = src[IDX(i + 2*S*M)];
        if constexpr (R >= 4) a3 = src[IDX(i + 3*S*M)];
        if constexpr (R >= 5) a4 = src[IDX(i + 4*S*M)];

        float2 b0, b1, b2, b3, b4;
        if constexpr (R == 2) {
            b0 = cadd(a0, a1); b1 = csub(a0, a1);
        } else if constexpr (R == 3) {
            constexpr float s3 = (float)DIR * 0.8660254037844386f;
            float2 t = cadd(a1, a2), u = csub(a1, a2);
            float2 mm = make_float2(a0.x - 0.5f*t.x, a0.y - 0.5f*t.y);
            float2 iu = make_float2(-s3*u.y, s3*u.x);
            b0 = cadd(a0, t); b1 = cadd(mm, iu); b2 = csub(mm, iu);
        } else if constexpr (R == 4) {
            float2 t0 = cadd(a0,a2), t1 = csub(a0,a2), t2 = cadd(a1,a3), t3 = csub(a1,a3);
            float2 j3 = make_float2(-(float)DIR*t3.y, (float)DIR*t3.x);
            b0 = cadd(t0,t2); b2 = csub(t0,t2); b1 = cadd(t1,j3); b3 = csub(t1,j3);
        } else { // R == 5
            constexpr float C1 = 0.30901699437494742f, S1c = 0.9510565162951535f;
            constexpr float C2 = -0.8090169943749475f, S2c = 0.5877852522924731f;
            float2 t1 = cadd(a1,a4), t2 = cadd(a2,a3), d1 = csub(a1,a4), d2 = csub(a2,a3);
            float2 m1 = make_float2(a0.x + C1*t1.x + C2*t2.x, a0.y + C1*t1.y + C2*t2.y);
            float2 m2 = make_float2(a0.x + C2*t1.x + C1*t2.x, a0.y + C2*t1.y + C1*t2.y);
            float2 e1 = make_float2(S1c*d1.x + S2c*d2.x, S1c*d1.y + S2c*d2.y);
            float2 e2 = make_float2(S2c*d1.x - S1c*d2.x, S2c*d1.y - S1c*d2.y);
            float2 ie1 = make_float2(-(float)DIR*e1.y, (float)DIR*e1.x);
            float2 ie2 = make_float2(-(float)DIR*e2.y, (float)DIR*e2.x);
            b0 = make_float2(a0.x + t1.x + t2.x, a0.y + t1.y + t2.y);
            b1 = cadd(m1, ie1); b4 = csub(m1, ie1);
            b2 = cadd(m2, ie2); b3 = csub(m2, ie2);
        }

        float sv, cv;
        __sincosf(STEP * (float)p, &sv, &cv);
        float2 w1 = make_float2(cv, sv);
        b1 = cmul(b1, w1);
        if constexpr (R >= 3) {
            float2 w2 = cmul(w1, w1); b2 = cmul(b2, w2);
            if constexpr (R >= 4) { float2 w3 = cmul(w2, w1); b3 = cmul(b3, w3); }
            if constexpr (R >= 5) { float2 w4 = cmul(w2, w2); b4 = cmul(b4, w4); }
        }

        const int ob = (i - p*S) + S*(R*p);
        dst[IDX(ob)]       = b0;
        dst[IDX(ob + S)]   = b1;
        if constexpr (R >= 3) dst[IDX(ob + 2*S)] = b2;
        if constexpr (R >= 4) dst[IDX(ob + 3*S)] = b3;
        if constexpr (R >= 5) dst[IDX(ob + 4*S)] = b4;
    }
}

// Remaining stages after a custom stage 1. Input in bA, result lands in bB.
template<int DIR, int B>
__device__ __forceinline__ void fft1080_rest(float2* bA, float2* bB, int tid){
    do_stage<DIR,3,270,  4*B>(bA,bB,tid,256); __syncthreads();
    do_stage<DIR,3, 90, 12*B>(bB,bA,tid,256); __syncthreads();
    do_stage<DIR,3, 30, 36*B>(bA,bB,tid,256); __syncthreads();
    do_stage<DIR,2, 10,108*B>(bB,bA,tid,256); __syncthreads();
    do_stage<DIR,5,  5,216*B>(bA,bB,tid,256); __syncthreads();
}

template<int DIR>
__device__ __forceinline__ void fft1920_rest(float2* bA, float2* bB, int tid){
    do_stage<DIR,4,480,  4>(bA,bB,tid,256); __syncthreads();
    do_stage<DIR,4,120, 16>(bB,bA,tid,256); __syncthreads();
    do_stage<DIR,2, 30, 64>(bA,bB,tid,256); __syncthreads();
    do_stage<DIR,3, 15,128>(bB,bA,tid,256); __syncthreads();
    do_stage<DIR,5,  5,384>(bA,bB,tid,256); __syncthreads();
}

// Column fwd stage 1 (radix-4, N=1080, S=B), DIR=-1, padded rows: a0=a3=0.
// Reads global rows 0..539 (= padded rows 270..809), cols c0..c0+B-1.
template<int B>
__device__ __forceinline__ void col_stage1_fwd(const float2* __restrict__ gsrc,
                                               int c0, float2* bA, int tid)
{
    constexpr float STEP = -PI2 / 1080.0f;
    for (int i = tid; i < 270*B; i += 256) {
        const int p = i / B, q = i - p*B;
        float2 a1 = gsrc[p*1920 + c0 + q];
        float2 a2 = gsrc[(p+270)*1920 + c0 + q];
        // radix-4, DIR=-1, a0=a3=0
        float2 j3 = make_float2(a1.y, -a1.x);
        float2 b0 = cadd(a2, a1);
        float2 b2 = csub(a2, a1);
        float2 t1 = make_float2(-a2.x, -a2.y);
        float2 b1 = cadd(t1, j3);
        float2 b3 = csub(t1, j3);
        float sv, cv; __sincosf(STEP * (float)p, &sv, &cv);
        float2 w1 = make_float2(cv, sv);
        float2 w2 = cmul(w1, w1), w3 = cmul(w2, w1);
        b1 = cmul(b1, w1); b2 = cmul(b2, w2); b3 = cmul(b3, w3);
        const int ob = q + B*4*p;
        bA[IDX(ob)] = b0; bA[IDX(ob+B)] = b1; bA[IDX(ob+2*B)] = b2; bA[IDX(ob+3*B)] = b3;
    }
}

// Column inverse stage 1 with fused K-multiply (radix-4, N=1080, S=B, DIR=+1).
// Reads natural-order spectrum from bSrc, multiplies by KT[c][k], writes bDst.
template<int B>
__device__ __forceinline__ void col_stage1_inv_mulK(const float2* __restrict__ bSrc,
                                                    float2* __restrict__ bDst,
                                                    const float2* __restrict__ KT,
                                                    int c0, int tid)
{
    constexpr float STEP = PI2 / 1080.0f;
    for (int i = tid; i < 270*B; i += 256) {
        const int p = i / B, q = i - p*B;
        const float2* Kc = KT + (c0+q)*1080 + p;
        float2 a0 = cmul(bSrc[IDX(i)],         Kc[0]);
        float2 a1 = cmul(bSrc[IDX(i+270*B)],   Kc[270]);
        float2 a2 = cmul(bSrc[IDX(i+540*B)],   Kc[540]);
        float2 a3 = cmul(bSrc[IDX(i+810*B)],   Kc[810]);
        float2 t0 = cadd(a0,a2), t1 = csub(a0,a2), t2 = cadd(a1,a3), t3 = csub(a1,a3);
        float2 j3 = make_float2(-t3.y, t3.x);   // DIR=+1
        float2 b0 = cadd(t0,t2), b2 = csub(t0,t2), b1 = cadd(t1,j3), b3 = csub(t1,j3);
        float sv, cv; __sincosf(STEP * (float)p, &sv, &cv);
        float2 w1 = make_float2(cv, sv);
        float2 w2 = cmul(w1, w1), w3 = cmul(w2, w1);
        b1 = cmul(b1, w1); b2 = cmul(b2, w2); b3 = cmul(b3, w3);
        const int ob = q + B*4*p;
        bDst[IDX(ob)] = b0; bDst[IDX(ob+B)] = b1; bDst[IDX(ob+2*B)] = b2; bDst[IDX(ob+3*B)] = b3;
    }
}

// Row fwd stage 1 (radix-4, N=1920, S=1), DIR=-1, padded cols: a0=a3=0.
// a1 = x[p], a2 = x[p+480] (x occupies padded cols 480..1439).
template<bool HASB>
__device__ __forceinline__ void row_stage1_fwd(const float* __restrict__ xa,
                                               const float* __restrict__ xb,
                                               float2* bA, int tid)
{
    constexpr float STEP = -PI2 / 1920.0f;
    for (int p = tid; p < 480; p += 256) {
        float2 a1 = make_float2(xa[p],     HASB ? xb[p]     : 0.f);
        float2 a2 = make_float2(xa[p+480], HASB ? xb[p+480] : 0.f);
        float2 j3 = make_float2(a1.y, -a1.x);
        float2 b0 = cadd(a2, a1);
        float2 b2 = csub(a2, a1);
        float2 t1 = make_float2(-a2.x, -a2.y);
        float2 b1 = cadd(t1, j3);
        float2 b3 = csub(t1, j3);
        float sv, cv; __sincosf(STEP * (float)p, &sv, &cv);
        float2 w1 = make_float2(cv, sv);
        float2 w2 = cmul(w1, w1), w3 = cmul(w2, w1);
        b1 = cmul(b1, w1); b2 = cmul(b2, w2); b3 = cmul(b3, w3);
        const int ob = 4*p;
        bA[IDX(ob)] = b0; bA[IDX(ob+1)] = b1; bA[IDX(ob+2)] = b2; bA[IDX(ob+3)] = b3;
    }
}

// Row inverse stage 1 (radix-4, N=1920, S=1, DIR=+1), full input from global.
__device__ __forceinline__ void row_stage1_inv_g(const float2* __restrict__ Zp,
                                                 float2* bA, int tid)
{
    constexpr float STEP = PI2 / 1920.0f;
    for (int p = tid; p < 480; p += 256) {
        float2 a0 = Zp[p], a1 = Zp[p+480], a2 = Zp[p+960], a3 = Zp[p+1440];
        float2 t0 = cadd(a0,a2), t1 = csub(a0,a2), t2 = cadd(a1,a3), t3 = csub(a1,a3);
        float2 j3 = make_float2(-t3.y, t3.x);
        float2 b0 = cadd(t0,t2), b2 = csub(t0,t2), b1 = cadd(t1,j3), b3 = csub(t1,j3);
        float sv, cv; __sincosf(STEP * (float)p, &sv, &cv);
        float2 w1 = make_float2(cv, sv);
        float2 w2 = cmul(w1, w1), w3 = cmul(w2, w1);
        b1 = cmul(b1, w1); b2 = cmul(b2, w2); b3 = cmul(b3, w3);
        const int ob = 4*p;
        bA[IDX(ob)] = b0; bA[IDX(ob+1)] = b1; bA[IDX(ob+2)] = b2; bA[IDX(ob+3)] = b3;
    }
}

// K1: row FFTs of padded h. Hrow[r][k], r=0..539 = padded row 270+r.
__global__ __launch_bounds__(256,5) void k_row_fft_h(const float* __restrict__ h,
                                                     float2* __restrict__ Hrow)
{
    __shared__ float2 bA[IDXSZ(1920)], bB[IDXSZ(1920)];
    const int tid = threadIdx.x, r = blockIdx.x;
    row_stage1_fwd<false>(h + r*960, nullptr, bA, tid);
    __syncthreads();
    fft1920_rest<-1>(bA, bB, tid);
    for (int i = tid; i < 1920; i += 256) Hrow[r*1920 + i] = bB[IDX(i)];
}

// K2: column FFTs of Hrow (B=2 cols/block) + build K transposed KT[c][k].
__global__ __launch_bounds__(256,4) void k_col_fft_h_buildK(const float2* __restrict__ Hrow,
                                                            const float* __restrict__ mu1,
                                                            float2* __restrict__ KT)
{
    constexpr int B = 2;
    __shared__ float2 bA[IDXSZ(1080*B)], bB[IDXSZ(1080*B)];
    const int tid = threadIdx.x;
    const int c0 = blockIdx.x * B;
    col_stage1_fwd<B>(Hrow, c0, bA, tid);
    __syncthreads();
    fft1080_rest<-1,B>(bA, bB, tid);
    const float sc = mu1[4] / ((1.0f + 1e-6f) * 2073600.0f);
    for (int i = tid; i < 1080*B; i += 256) {
        int k = i / B, c = c0 + (i - (i/B)*B);
        float2 Hv = bB[IDX(i)];
        float mag2 = Hv.x*Hv.x + Hv.y*Hv.y;
        float ps = 4.0f - 2.0f*__cosf(PI2 * (float)k * (1.0f/1080.0f))
                        - 2.0f*__cosf(PI2 * (float)c * (1.0f/1920.0f));
        float rdiv = 1.0f / (1e-6f*mag2 + 1e-5f*ps + 4e-5f);
        float f = sc * rdiv;
        KT[c*1080 + k] = make_float2(f*Hv.x, -f*Hv.y);
    }
}

// K3: row FFTs of padded x, pairs packed z = x_a + i*x_b.
__global__ __launch_bounds__(256,5) void k_row_fft_x(const float* __restrict__ x,
                                                     float2* __restrict__ Z)
{
    __shared__ float2 bA[IDXSZ(1920)], bB[IDXSZ(1920)];
    const int tid = threadIdx.x;
    const int p = blockIdx.x / 540;
    const int r = blockIdx.x % 540;
    row_stage1_fwd<true>(x + ((2*p)*540 + r)*960, x + ((2*p+1)*540 + r)*960, bA, tid);
    __syncthreads();
    fft1920_rest<-1>(bA, bB, tid);
    float2* Zp = Z + (p*540 + r)*1920;
    for (int i = tid; i < 1920; i += 256) Zp[i] = bB[IDX(i)];
}

// K4: fused column pass: FFT(1080) -> *K -> IFFT(1080), B=2 cols/block,
// in-place on Z; crop row remap (ir+810)%1080 folded into write-back.
__global__ __launch_bounds__(256,4) void k_col_fused(float2* __restrict__ Z,
                                                     const float2* __restrict__ KT)
{
    constexpr int B = 2;
    __shared__ float2 bA[IDXSZ(1080*B)], bB[IDXSZ(1080*B)];
    const int tid = threadIdx.x;
    const int p  = blockIdx.x / (1920/B);
    const int c0 = (blockIdx.x % (1920/B)) * B;
    float2* Zp = Z + p*540*1920;
    col_stage1_fwd<B>(Zp, c0, bA, tid);
    __syncthreads();
    fft1080_rest<-1,B>(bA, bB, tid);          // fwd spectrum in bB (natural)
    col_stage1_inv_mulK<B>(bB, bA, KT, c0, tid);
    __syncthreads();
    fft1080_rest<1,B>(bA, bB, tid);           // inverse result in bB
    for (int i = tid; i < 540*B; i += 256) {
        int ir = i / B, q = i - (i/B)*B;
        int src = (ir < 270) ? (ir + 810) : (ir - 270);
        Zp[ir*1920 + c0 + q] = bB[IDX(src*B + q)];
    }
}

// K5: row IFFTs + column crop remap + split pair into two real outputs.
__global__ __launch_bounds__(256,5) void k_row_ifft_out(const float2* __restrict__ Z,
                                                        float* __restrict__ out)
{
    __shared__ float2 bA[IDXSZ(1920)], bB[IDXSZ(1920)];
    const int tid = threadIdx.x;
    const int p = blockIdx.x / 540;
    const int r = blockIdx.x % 540;
    const float2* Zp = Z + (p*540 + r)*1920;
    row_stage1_inv_g(Zp, bA, tid);
    __syncthreads();
    fft1920_rest<1>(bA, bB, tid);
    float* oa = out + ((2*p)*540 + r)*960;
    float* ob = out + ((2*p+1)*540 + r)*960;
    for (int j = tid; j < 960; j += 256) {
        int src = (j < 480) ? (j + 1440) : (j - 480);
        float2 v = bB[IDX(src)];
        oa[j] = v.x;
        ob[j] = v.y;
    }
}

extern "C" void kernel_launch(void* const* d_in, const int* in_sizes, int n_in,
                              void* d_out, int out_size, void* d_ws, size_t ws_size,
                              hipStream_t stream)
{
    (void)in_sizes; (void)n_in; (void)out_size; (void)ws_size;
    const float* x   = (const float*)d_in[0];
    const float* h   = (const float*)d_in[1];
    const float* mu1 = (const float*)d_in[2];
    float*       out = (float*)d_out;

    // ws layout: KT (1080*1920 c64) | Z (4*540*1920 c64); Hrow aliases Z.
    float2* KT   = (float2*)d_ws;
    float2* Z    = KT + 1080*1920;
    float2* Hrow = Z;

    k_row_fft_h       <<<540,    256, 0, stream>>>(h, Hrow);
    k_col_fft_h_buildK<<<960,    256, 0, stream>>>(Hrow, mu1, KT);
    k_row_fft_x       <<<4*540,  256, 0, stream>>>(x, Z);
    k_col_fused       <<<4*960,  256, 0, stream>>>(Z, KT);
    k_row_ifft_out    <<<4*540,  256, 0, stream>>>(Z, out);
}

// Round 3
// 150.795 us; speedup vs baseline: 1.0708x; 1.0007x over previous
//
#include <hip/hip_runtime.h>

// Le-ADMM reduction: state resets each iteration => output is one linear
// circular filter: out = crop_shift( IFFT2( K . FFT2(pad(x)) ) ),
// K = mu1[4]/((1+1e-6)*FH*FW) * conj(Hp) / (1e-6|Hp|^2 + 1e-5*PsiTPsi + 4e-5).
// Pairs packed z = x_a + i*x_b (K Hermitian => both results real).
//
// R2: radix-6/8 4-stage FFTs (1080=6*6*6*5, 1920=8*8*6*5); stage-1 reads
// global directly (zero-pad specialized); final radix-5 stage computes in
// registers and stores straight to global (crop remap / K-build folded in);
// k_col_fused loops the 4 pairs per block for KT L2 reuse (grid 960).

#define PI2 6.2831853071795864f

__device__ __forceinline__ float2 cadd(float2 a, float2 b){ return make_float2(a.x+b.x, a.y+b.y); }
__device__ __forceinline__ float2 csub(float2 a, float2 b){ return make_float2(a.x-b.x, a.y-b.y); }
__device__ __forceinline__ float2 cmul(float2 a, float2 b){ return make_float2(a.x*b.x - a.y*b.y, a.x*b.y + a.y*b.x); }

// LDS pad: +1 element every 16 to break power-of-2 stride conflicts.
__device__ __forceinline__ int IDX(int a){ return a + (a >> 4); }
#define IDXSZ(n) ((n) + ((n) >> 4))

template<int DIR>
__device__ __forceinline__ void dft3(float2 x0, float2 x1, float2 x2,
                                     float2& y0, float2& y1, float2& y2)
{
    constexpr float s3 = (float)DIR * 0.8660254037844386f;
    float2 t = cadd(x1, x2), u = csub(x1, x2);
    float2 m = make_float2(x0.x - 0.5f*t.x, x0.y - 0.5f*t.y);
    float2 iu = make_float2(-s3*u.y, s3*u.x);
    y0 = cadd(x0, t); y1 = cadd(m, iu); y2 = csub(m, iu);
}

template<int DIR>
__device__ __forceinline__ void dft4(float2 a0, float2 a1, float2 a2, float2 a3,
                                     float2& b0, float2& b1, float2& b2, float2& b3)
{
    float2 t0 = cadd(a0,a2), t1 = csub(a0,a2), t2 = cadd(a1,a3), t3 = csub(a1,a3);
    float2 j3 = make_float2(-(float)DIR*t3.y, (float)DIR*t3.x);
    b0 = cadd(t0,t2); b2 = csub(t0,t2); b1 = cadd(t1,j3); b3 = csub(t1,j3);
}

template<int DIR>
__device__ __forceinline__ void dft6(const float2 a[6], float2 b[6])
{
    float2 e0,e1,e2,o0,o1,o2;
    dft3<DIR>(a[0],a[2],a[4], e0,e1,e2);
    dft3<DIR>(a[1],a[3],a[5], o0,o1,o2);
    constexpr float s3 = (float)DIR * 0.8660254037844386f;
    float2 w1 = make_float2( 0.5f, s3);   // exp(DIR*i*pi/3)
    float2 w2 = make_float2(-0.5f, s3);
    float2 t1 = cmul(w1,o1), t2 = cmul(w2,o2);
    b[0]=cadd(e0,o0); b[3]=csub(e0,o0);
    b[1]=cadd(e1,t1); b[4]=csub(e1,t1);
    b[2]=cadd(e2,t2); b[5]=csub(e2,t2);
}

template<int DIR>
__device__ __forceinline__ void dft8(const float2 a[8], float2 b[8])
{
    float2 e0,e1,e2,e3,o0,o1,o2,o3;
    dft4<DIR>(a[0],a[2],a[4],a[6], e0,e1,e2,e3);
    dft4<DIR>(a[1],a[3],a[5],a[7], o0,o1,o2,o3);
    constexpr float c = 0.70710678118654752f;
    float2 w1 = make_float2( c, (float)DIR*c);
    float2 w3 = make_float2(-c, (float)DIR*c);
    float2 t1 = cmul(w1,o1);
    float2 t2 = make_float2(-(float)DIR*o2.y, (float)DIR*o2.x);
    float2 t3 = cmul(w3,o3);
    b[0]=cadd(e0,o0); b[4]=csub(e0,o0);
    b[1]=cadd(e1,t1); b[5]=csub(e1,t1);
    b[2]=cadd(e2,t2); b[6]=csub(e2,t2);
    b[3]=cadd(e3,t3); b[7]=csub(e3,t3);
}

template<int DIR>
__device__ __forceinline__ void dft5(const float2 a[5], float2 b[5])
{
    constexpr float C1 = 0.30901699437494742f, S1c = 0.9510565162951535f;
    constexpr float C2 = -0.8090169943749475f, S2c = 0.5877852522924731f;
    float2 t1 = cadd(a[1],a[4]), t2 = cadd(a[2],a[3]), d1 = csub(a[1],a[4]), d2 = csub(a[2],a[3]);
    float2 m1 = make_float2(a[0].x + C1*t1.x + C2*t2.x, a[0].y + C1*t1.y + C2*t2.y);
    float2 m2 = make_float2(a[0].x + C2*t1.x + C1*t2.x, a[0].y + C2*t1.y + C1*t2.y);
    float2 e1 = make_float2(S1c*d1.x + S2c*d2.x, S1c*d1.y + S2c*d2.y);
    float2 e2 = make_float2(S2c*d1.x - S1c*d2.x, S2c*d1.y - S1c*d2.y);
    float2 ie1 = make_float2(-(float)DIR*e1.y, (float)DIR*e1.x);
    float2 ie2 = make_float2(-(float)DIR*e2.y, (float)DIR*e2.x);
    b[0] = make_float2(a[0].x + t1.x + t2.x, a[0].y + t1.y + t2.y);
    b[1] = cadd(m1, ie1); b[4] = csub(m1, ie1);
    b[2] = cadd(m2, ie2); b[3] = csub(m2, ie2);
}

// Generic middle Stockham stage (R = 6 or 8), LDS -> LDS.
template<int DIR, int R, int NCUR, int S>
__device__ __forceinline__ void mid_stage(const float2* __restrict__ src,
                                          float2* __restrict__ dst, int tid)
{
    constexpr int M  = NCUR / R;
    constexpr int NB = M * S;
    constexpr float STEP = (float)DIR * PI2 / (float)NCUR;
    for (int i = tid; i < NB; i += 256) {
        const int p = i / S;
        float2 a[R], b[R];
        #pragma unroll
        for (int t = 0; t < R; ++t) a[t] = src[IDX(i + S*M*t)];
        if constexpr (R == 6) dft6<DIR>(a,b); else dft8<DIR>(a,b);
        float sv, cv; __sincosf(STEP * (float)p, &sv, &cv);
        float2 w1 = make_float2(cv, sv), w = w1;
        b[1] = cmul(b[1], w);
        #pragma unroll
        for (int u = 2; u < R; ++u) { w = cmul(w, w1); b[u] = cmul(b[u], w); }
        const int ob = (i - p*S) + S*(R*p);
        #pragma unroll
        for (int u = 0; u < R; ++u) dst[IDX(ob + S*u)] = b[u];
    }
}

// ---------------- row (1920 = 8*8*6*5) pieces ----------------

// Stage 1, radix-8, S=1, from global; padded cols 480..1439 nonzero
// => a[2..5] = x[p], x[p+240], x[p+480], x[p+720]; rest 0.
template<bool HASB>
__device__ __forceinline__ void row_s1_fwd(const float* __restrict__ xa,
                                           const float* __restrict__ xb,
                                           float2* __restrict__ bA, int tid)
{
    constexpr float STEP = -PI2 / 1920.0f;
    const float2 z = make_float2(0.f,0.f);
    for (int p = tid; p < 240; p += 256) {
        float2 a[8], b[8];
        a[0]=z; a[1]=z; a[6]=z; a[7]=z;
        a[2] = make_float2(xa[p],     HASB ? xb[p]     : 0.f);
        a[3] = make_float2(xa[p+240], HASB ? xb[p+240] : 0.f);
        a[4] = make_float2(xa[p+480], HASB ? xb[p+480] : 0.f);
        a[5] = make_float2(xa[p+720], HASB ? xb[p+720] : 0.f);
        dft8<-1>(a,b);
        float sv, cv; __sincosf(STEP * (float)p, &sv, &cv);
        float2 w1 = make_float2(cv, sv), w = w1;
        b[1] = cmul(b[1], w);
        #pragma unroll
        for (int u = 2; u < 8; ++u) { w = cmul(w, w1); b[u] = cmul(b[u], w); }
        #pragma unroll
        for (int u = 0; u < 8; ++u) bA[IDX(8*p + u)] = b[u];
    }
}

// Stage 1, radix-8, S=1, inverse, full read from global spectrum.
__device__ __forceinline__ void row_s1_inv(const float2* __restrict__ Zp,
                                           float2* __restrict__ bA, int tid)
{
    constexpr float STEP = PI2 / 1920.0f;
    for (int p = tid; p < 240; p += 256) {
        float2 a[8], b[8];
        #pragma unroll
        for (int t = 0; t < 8; ++t) a[t] = Zp[p + 240*t];
        dft8<1>(a,b);
        float sv, cv; __sincosf(STEP * (float)p, &sv, &cv);
        float2 w1 = make_float2(cv, sv), w = w1;
        b[1] = cmul(b[1], w);
        #pragma unroll
        for (int u = 2; u < 8; ++u) { w = cmul(w, w1); b[u] = cmul(b[u], w); }
        #pragma unroll
        for (int u = 0; u < 8; ++u) bA[IDX(8*p + u)] = b[u];
    }
}

// Final stage, radix-5, S=384, p=0 (no twiddle): registers -> global natural.
template<int DIR>
__device__ __forceinline__ void row_fin5_store(const float2* __restrict__ src,
                                               float2* __restrict__ gdst, int tid)
{
    for (int q = tid; q < 384; q += 256) {
        float2 a[5], b[5];
        #pragma unroll
        for (int u = 0; u < 5; ++u) a[u] = src[IDX(q + 384*u)];
        dft5<DIR>(a,b);
        #pragma unroll
        for (int u = 0; u < 5; ++u) gdst[q + 384*u] = b[u];
    }
}

// ---------------- column (1080 = 6*6*6*5, B=2 cols interleaved) pieces ------

// Stage 1, radix-6, S=2, from global; padded rows 270..809 nonzero:
// a1 = g[p-90] (p>=90), a2 = g[p+90], a3 = g[p+270], a4 = g[p+450] (p<90).
__device__ __forceinline__ void col_s1_fwd(const float2* __restrict__ g, int c0,
                                           float2* __restrict__ bA, int tid)
{
    constexpr float STEP = -PI2 / 1080.0f;
    const float2 z = make_float2(0.f,0.f);
    for (int i = tid; i < 360; i += 256) {
        const int p = i >> 1, q = i & 1;
        const float2* gc = g + c0 + q;
        float2 a[6], b[6];
        a[0] = z; a[5] = z;
        a[1] = (p >= 90) ? gc[(p-90)*1920]  : z;
        a[2] = gc[(p+90)*1920];
        a[3] = gc[(p+270)*1920];
        a[4] = (p < 90)  ? gc[(p+450)*1920] : z;
        dft6<-1>(a,b);
        float sv, cv; __sincosf(STEP * (float)p, &sv, &cv);
        float2 w1 = make_float2(cv, sv), w = w1;
        b[1] = cmul(b[1], w);
        #pragma unroll
        for (int u = 2; u < 6; ++u) { w = cmul(w, w1); b[u] = cmul(b[u], w); }
        const int ob = q + 12*p;
        #pragma unroll
        for (int u = 0; u < 6; ++u) bA[IDX(ob + 2*u)] = b[u];
    }
}

// Inverse stage 1, radix-6, with fused K-multiply (reads natural spectrum).
__device__ __forceinline__ void col_s1_inv_mulK(const float2* __restrict__ bSrc,
                                                float2* __restrict__ bDst,
                                                const float2* __restrict__ KT,
                                                int c0, int tid)
{
    constexpr float STEP = PI2 / 1080.0f;
    for (int i = tid; i < 360; i += 256) {
        const int p = i >> 1, q = i & 1;
        const float2* Kc = KT + (c0 + q)*1080 + p;
        float2 a[6], b[6];
        #pragma unroll
        for (int t = 0; t < 6; ++t) a[t] = cmul(bSrc[IDX(i + 360*t)], Kc[180*t]);
        dft6<1>(a,b);
        float sv, cv; __sincosf(STEP * (float)p, &sv, &cv);
        float2 w1 = make_float2(cv, sv), w = w1;
        b[1] = cmul(b[1], w);
        #pragma unroll
        for (int u = 2; u < 6; ++u) { w = cmul(w, w1); b[u] = cmul(b[u], w); }
        const int ob = q + 12*p;
        #pragma unroll
        for (int u = 0; u < 6; ++u) bDst[IDX(ob + 2*u)] = b[u];
    }
}

// Forward final stage, radix-5, S=432, p=0: LDS -> LDS (spectrum for mulK).
template<int DIR>
__device__ __forceinline__ void col_fin5_lds(const float2* __restrict__ src,
                                             float2* __restrict__ dst, int tid)
{
    for (int q = tid; q < 432; q += 256) {
        float2 a[5], b[5];
        #pragma unroll
        for (int u = 0; u < 5; ++u) a[u] = src[IDX(q + 432*u)];
        dft5<DIR>(a,b);
        #pragma unroll
        for (int u = 0; u < 5; ++u) dst[IDX(q + 432*u)] = b[u];
    }
}

// Inverse final stage, radix-5, fused crop (row remap (k+810)%1080) + store.
// k = (q>>1) + 216u; needed rows: u=0 (ir=k+270), u=1 if qk<54 (ir=k+270),
// u=3 if qk>=162 (ir=k-810), u=4 (ir=k-810).
__device__ __forceinline__ void col_fin5_crop_store(const float2* __restrict__ src,
                                                    float2* __restrict__ Zp,
                                                    int c0, int tid)
{
    for (int q = tid; q < 432; q += 256) {
        float2 a[5], b[5];
        #pragma unroll
        for (int u = 0; u < 5; ++u) a[u] = src[IDX(q + 432*u)];
        dft5<1>(a,b);
        const int qk = q >> 1, c = c0 + (q & 1);
        Zp[(qk + 270)*1920 + c] = b[0];
        if (qk < 54)   Zp[(qk + 486)*1920 + c] = b[1];
        if (qk >= 162) Zp[(qk - 162)*1920 + c] = b[3];
        Zp[(qk + 54)*1920 + c]  = b[4];
    }
}

// ---------------- kernels ----------------

// K1: row FFTs of padded h. Hrow[r][k], r=0..539 = padded row 270+r.
__global__ __launch_bounds__(256,5) void k_row_fft_h(const float* __restrict__ h,
                                                     float2* __restrict__ Hrow)
{
    __shared__ float2 bA[IDXSZ(1920)], bB[IDXSZ(1920)];
    const int tid = threadIdx.x, r = blockIdx.x;
    row_s1_fwd<false>(h + r*960, nullptr, bA, tid); __syncthreads();
    mid_stage<-1,8,240, 8>(bA, bB, tid); __syncthreads();
    mid_stage<-1,6, 30,64>(bB, bA, tid); __syncthreads();
    row_fin5_store<-1>(bA, Hrow + r*1920, tid);
}

// K2: column FFTs of Hrow (2 cols/block) + build KT[c][k] from registers.
__global__ __launch_bounds__(256,4) void k_col_fft_h_buildK(const float2* __restrict__ Hrow,
                                                            const float* __restrict__ mu1,
                                                            float2* __restrict__ KT)
{
    __shared__ float2 bA[IDXSZ(2160)], bB[IDXSZ(2160)];
    const int tid = threadIdx.x;
    const int c0 = blockIdx.x * 2;
    col_s1_fwd(Hrow, c0, bA, tid); __syncthreads();
    mid_stage<-1,6,180,12>(bA, bB, tid); __syncthreads();
    mid_stage<-1,6, 30,72>(bB, bA, tid); __syncthreads();
    const float sc = mu1[4] / ((1.0f + 1e-6f) * 2073600.0f);
    for (int q = tid; q < 432; q += 256) {
        float2 a[5], b[5];
        #pragma unroll
        for (int u = 0; u < 5; ++u) a[u] = bA[IDX(q + 432*u)];
        dft5<-1>(a,b);
        const int qk = q >> 1, c = c0 + (q & 1);
        const float cosc = __cosf(PI2 * (float)c * (1.0f/1920.0f));
        #pragma unroll
        for (int u = 0; u < 5; ++u) {
            const int k = qk + 216*u;
            float2 Hv = b[u];
            float mag2 = Hv.x*Hv.x + Hv.y*Hv.y;
            float ps = 4.0f - 2.0f*__cosf(PI2 * (float)k * (1.0f/1080.0f)) - 2.0f*cosc;
            float f = sc / (1e-6f*mag2 + 1e-5f*ps + 4e-5f);
            KT[c*1080 + k] = make_float2(f*Hv.x, -f*Hv.y);
        }
    }
}

// K3: row FFTs of padded x, pairs packed z = x_a + i*x_b.
__global__ __launch_bounds__(256,5) void k_row_fft_x(const float* __restrict__ x,
                                                     float2* __restrict__ Z)
{
    __shared__ float2 bA[IDXSZ(1920)], bB[IDXSZ(1920)];
    const int tid = threadIdx.x;
    const int p = blockIdx.x / 540;
    const int r = blockIdx.x % 540;
    row_s1_fwd<true>(x + ((2*p)*540 + r)*960, x + ((2*p+1)*540 + r)*960, bA, tid);
    __syncthreads();
    mid_stage<-1,8,240, 8>(bA, bB, tid); __syncthreads();
    mid_stage<-1,6, 30,64>(bB, bA, tid); __syncthreads();
    row_fin5_store<-1>(bA, Z + (p*540 + r)*1920, tid);
}

// K4: fused column pass, 2 cols/block, all 4 pairs looped per block
// (KT slice stays hot in this XCD's L2 across pairs).
__global__ __launch_bounds__(256,4) void k_col_fused(float2* __restrict__ Z,
                                                     const float2* __restrict__ KT)
{
    __shared__ float2 bA[IDXSZ(2160)], bB[IDXSZ(2160)];
    const int tid = threadIdx.x;
    const int c0 = blockIdx.x * 2;
    for (int pp = 0; pp < 4; ++pp) {
        float2* Zp = Z + pp*540*1920;
        col_s1_fwd(Zp, c0, bA, tid);          __syncthreads();
        mid_stage<-1,6,180,12>(bA, bB, tid);  __syncthreads();
        mid_stage<-1,6, 30,72>(bB, bA, tid);  __syncthreads();
        col_fin5_lds<-1>(bA, bB, tid);        __syncthreads();
        col_s1_inv_mulK(bB, bA, KT, c0, tid); __syncthreads();
        mid_stage<1,6,180,12>(bA, bB, tid);   __syncthreads();
        mid_stage<1,6, 30,72>(bB, bA, tid);   __syncthreads();
        col_fin5_crop_store(bA, Zp, c0, tid); __syncthreads();
    }
}

// K5: row IFFTs + column crop remap + split pair into two real outputs.
// Final radix-5 stage fused with crop-store: n=q+384u ->
// u=0: j=q+480; u=1(q<96): j=q+864; u=3(q>=288): j=q-288; u=4: j=q+96.
__global__ __launch_bounds__(256,5) void k_row_ifft_out(const float2* __restrict__ Z,
                                                        float* __restrict__ out)
{
    __shared__ float2 bA[IDXSZ(1920)], bB[IDXSZ(1920)];
    const int tid = threadIdx.x;
    const int p = blockIdx.x / 540;
    const int r = blockIdx.x % 540;
    row_s1_inv(Z + (p*540 + r)*1920, bA, tid); __syncthreads();
    mid_stage<1,8,240, 8>(bA, bB, tid); __syncthreads();
    mid_stage<1,6, 30,64>(bB, bA, tid); __syncthreads();
    float* oa = out + ((2*p)*540 + r)*960;
    float* ob = out + ((2*p+1)*540 + r)*960;
    for (int q = tid; q < 384; q += 256) {
        float2 a[5], b[5];
        #pragma unroll
        for (int u = 0; u < 5; ++u) a[u] = bA[IDX(q + 384*u)];
        dft5<1>(a,b);
        oa[q+480] = b[0].x; ob[q+480] = b[0].y;
        if (q < 96)   { oa[q+864] = b[1].x; ob[q+864] = b[1].y; }
        if (q >= 288) { oa[q-288] = b[3].x; ob[q-288] = b[3].y; }
        oa[q+96]  = b[4].x; ob[q+96]  = b[4].y;
    }
}

extern "C" void kernel_launch(void* const* d_in, const int* in_sizes, int n_in,
                              void* d_out, int out_size, void* d_ws, size_t ws_size,
                              hipStream_t stream)
{
    (void)in_sizes; (void)n_in; (void)out_size; (void)ws_size;
    const float* x   = (const float*)d_in[0];
    const float* h   = (const float*)d_in[1];
    const float* mu1 = (const float*)d_in[2];
    float*       out = (float*)d_out;

    // ws layout: KT (1080*1920 c64) | Z (4*540*1920 c64); Hrow aliases Z.
    float2* KT   = (float2*)d_ws;
    float2* Z    = KT + 1080*1920;
    float2* Hrow = Z;

    k_row_fft_h       <<<540,    256, 0, stream>>>(h, Hrow);
    k_col_fft_h_buildK<<<960,    256, 0, stream>>>(Hrow, mu1, KT);
    k_row_fft_x       <<<4*540,  256, 0, stream>>>(x, Z);
    k_col_fused       <<<960,    256, 0, stream>>>(Z, KT);
    k_row_ifft_out    <<<4*540,  256, 0, stream>>>(Z, out);
}

// Round 4
// 100.193 us; speedup vs baseline: 1.6116x; 1.5050x over previous
//
#include <hip/hip_runtime.h>

// Le-ADMM reduction: state resets each iteration => output is one linear
// circular filter: out = crop_shift( IFFT2( K . FFT2(pad(x)) ) ),
// K = mu1[4]/((1+1e-6)*FH*FW) * conj(Hp) / (1e-6|Hp|^2 + 1e-5*PsiTPsi + 4e-5).
// Pairs packed z = x_a + i*x_b (K Hermitian => both results real).
//
// R3: k_col_fused back to 1 pair/block (grid 3840) + chunked XCD swizzle:
// xcd = bid&7 owns columns [xcd*240, xcd*240+240) for all 4 pairs, so the
// 4 blocks sharing each 64B Z cache line sit on ONE XCD (L2 absorbs the
// re-reads; R2 measured 4x Z over-fetch from cross-XCD sharing), and the
// XCD's 2MB KT slab stays L2-resident across pairs. Same swizzle for K2.

#define PI2 6.2831853071795864f

__device__ __forceinline__ float2 cadd(float2 a, float2 b){ return make_float2(a.x+b.x, a.y+b.y); }
__device__ __forceinline__ float2 csub(float2 a, float2 b){ return make_float2(a.x-b.x, a.y-b.y); }
__device__ __forceinline__ float2 cmul(float2 a, float2 b){ return make_float2(a.x*b.x - a.y*b.y, a.x*b.y + a.y*b.x); }

// LDS pad: +1 element every 16 to break power-of-2 stride conflicts.
__device__ __forceinline__ int IDX(int a){ return a + (a >> 4); }
#define IDXSZ(n) ((n) + ((n) >> 4))

template<int DIR>
__device__ __forceinline__ void dft3(float2 x0, float2 x1, float2 x2,
                                     float2& y0, float2& y1, float2& y2)
{
    constexpr float s3 = (float)DIR * 0.8660254037844386f;
    float2 t = cadd(x1, x2), u = csub(x1, x2);
    float2 m = make_float2(x0.x - 0.5f*t.x, x0.y - 0.5f*t.y);
    float2 iu = make_float2(-s3*u.y, s3*u.x);
    y0 = cadd(x0, t); y1 = cadd(m, iu); y2 = csub(m, iu);
}

template<int DIR>
__device__ __forceinline__ void dft4(float2 a0, float2 a1, float2 a2, float2 a3,
                                     float2& b0, float2& b1, float2& b2, float2& b3)
{
    float2 t0 = cadd(a0,a2), t1 = csub(a0,a2), t2 = cadd(a1,a3), t3 = csub(a1,a3);
    float2 j3 = make_float2(-(float)DIR*t3.y, (float)DIR*t3.x);
    b0 = cadd(t0,t2); b2 = csub(t0,t2); b1 = cadd(t1,j3); b3 = csub(t1,j3);
}

template<int DIR>
__device__ __forceinline__ void dft6(const float2 a[6], float2 b[6])
{
    float2 e0,e1,e2,o0,o1,o2;
    dft3<DIR>(a[0],a[2],a[4], e0,e1,e2);
    dft3<DIR>(a[1],a[3],a[5], o0,o1,o2);
    constexpr float s3 = (float)DIR * 0.8660254037844386f;
    float2 w1 = make_float2( 0.5f, s3);   // exp(DIR*i*pi/3)
    float2 w2 = make_float2(-0.5f, s3);
    float2 t1 = cmul(w1,o1), t2 = cmul(w2,o2);
    b[0]=cadd(e0,o0); b[3]=csub(e0,o0);
    b[1]=cadd(e1,t1); b[4]=csub(e1,t1);
    b[2]=cadd(e2,t2); b[5]=csub(e2,t2);
}

template<int DIR>
__device__ __forceinline__ void dft8(const float2 a[8], float2 b[8])
{
    float2 e0,e1,e2,e3,o0,o1,o2,o3;
    dft4<DIR>(a[0],a[2],a[4],a[6], e0,e1,e2,e3);
    dft4<DIR>(a[1],a[3],a[5],a[7], o0,o1,o2,o3);
    constexpr float c = 0.70710678118654752f;
    float2 w1 = make_float2( c, (float)DIR*c);
    float2 w3 = make_float2(-c, (float)DIR*c);
    float2 t1 = cmul(w1,o1);
    float2 t2 = make_float2(-(float)DIR*o2.y, (float)DIR*o2.x);
    float2 t3 = cmul(w3,o3);
    b[0]=cadd(e0,o0); b[4]=csub(e0,o0);
    b[1]=cadd(e1,t1); b[5]=csub(e1,t1);
    b[2]=cadd(e2,t2); b[6]=csub(e2,t2);
    b[3]=cadd(e3,t3); b[7]=csub(e3,t3);
}

template<int DIR>
__device__ __forceinline__ void dft5(const float2 a[5], float2 b[5])
{
    constexpr float C1 = 0.30901699437494742f, S1c = 0.9510565162951535f;
    constexpr float C2 = -0.8090169943749475f, S2c = 0.5877852522924731f;
    float2 t1 = cadd(a[1],a[4]), t2 = cadd(a[2],a[3]), d1 = csub(a[1],a[4]), d2 = csub(a[2],a[3]);
    float2 m1 = make_float2(a[0].x + C1*t1.x + C2*t2.x, a[0].y + C1*t1.y + C2*t2.y);
    float2 m2 = make_float2(a[0].x + C2*t1.x + C1*t2.x, a[0].y + C2*t1.y + C1*t2.y);
    float2 e1 = make_float2(S1c*d1.x + S2c*d2.x, S1c*d1.y + S2c*d2.y);
    float2 e2 = make_float2(S2c*d1.x - S1c*d2.x, S2c*d1.y - S1c*d2.y);
    float2 ie1 = make_float2(-(float)DIR*e1.y, (float)DIR*e1.x);
    float2 ie2 = make_float2(-(float)DIR*e2.y, (float)DIR*e2.x);
    b[0] = make_float2(a[0].x + t1.x + t2.x, a[0].y + t1.y + t2.y);
    b[1] = cadd(m1, ie1); b[4] = csub(m1, ie1);
    b[2] = cadd(m2, ie2); b[3] = csub(m2, ie2);
}

// Generic middle Stockham stage (R = 6 or 8), LDS -> LDS.
template<int DIR, int R, int NCUR, int S>
__device__ __forceinline__ void mid_stage(const float2* __restrict__ src,
                                          float2* __restrict__ dst, int tid)
{
    constexpr int M  = NCUR / R;
    constexpr int NB = M * S;
    constexpr float STEP = (float)DIR * PI2 / (float)NCUR;
    for (int i = tid; i < NB; i += 256) {
        const int p = i / S;
        float2 a[R], b[R];
        #pragma unroll
        for (int t = 0; t < R; ++t) a[t] = src[IDX(i + S*M*t)];
        if constexpr (R == 6) dft6<DIR>(a,b); else dft8<DIR>(a,b);
        float sv, cv; __sincosf(STEP * (float)p, &sv, &cv);
        float2 w1 = make_float2(cv, sv), w = w1;
        b[1] = cmul(b[1], w);
        #pragma unroll
        for (int u = 2; u < R; ++u) { w = cmul(w, w1); b[u] = cmul(b[u], w); }
        const int ob = (i - p*S) + S*(R*p);
        #pragma unroll
        for (int u = 0; u < R; ++u) dst[IDX(ob + S*u)] = b[u];
    }
}

// ---------------- row (1920 = 8*8*6*5) pieces ----------------

// Stage 1, radix-8, S=1, from global; padded cols 480..1439 nonzero
// => a[2..5] = x[p], x[p+240], x[p+480], x[p+720]; rest 0.
template<bool HASB>
__device__ __forceinline__ void row_s1_fwd(const float* __restrict__ xa,
                                           const float* __restrict__ xb,
                                           float2* __restrict__ bA, int tid)
{
    constexpr float STEP = -PI2 / 1920.0f;
    const float2 z = make_float2(0.f,0.f);
    for (int p = tid; p < 240; p += 256) {
        float2 a[8], b[8];
        a[0]=z; a[1]=z; a[6]=z; a[7]=z;
        a[2] = make_float2(xa[p],     HASB ? xb[p]     : 0.f);
        a[3] = make_float2(xa[p+240], HASB ? xb[p+240] : 0.f);
        a[4] = make_float2(xa[p+480], HASB ? xb[p+480] : 0.f);
        a[5] = make_float2(xa[p+720], HASB ? xb[p+720] : 0.f);
        dft8<-1>(a,b);
        float sv, cv; __sincosf(STEP * (float)p, &sv, &cv);
        float2 w1 = make_float2(cv, sv), w = w1;
        b[1] = cmul(b[1], w);
        #pragma unroll
        for (int u = 2; u < 8; ++u) { w = cmul(w, w1); b[u] = cmul(b[u], w); }
        #pragma unroll
        for (int u = 0; u < 8; ++u) bA[IDX(8*p + u)] = b[u];
    }
}

// Stage 1, radix-8, S=1, inverse, full read from global spectrum.
__device__ __forceinline__ void row_s1_inv(const float2* __restrict__ Zp,
                                           float2* __restrict__ bA, int tid)
{
    constexpr float STEP = PI2 / 1920.0f;
    for (int p = tid; p < 240; p += 256) {
        float2 a[8], b[8];
        #pragma unroll
        for (int t = 0; t < 8; ++t) a[t] = Zp[p + 240*t];
        dft8<1>(a,b);
        float sv, cv; __sincosf(STEP * (float)p, &sv, &cv);
        float2 w1 = make_float2(cv, sv), w = w1;
        b[1] = cmul(b[1], w);
        #pragma unroll
        for (int u = 2; u < 8; ++u) { w = cmul(w, w1); b[u] = cmul(b[u], w); }
        #pragma unroll
        for (int u = 0; u < 8; ++u) bA[IDX(8*p + u)] = b[u];
    }
}

// Final stage, radix-5, S=384, p=0 (no twiddle): registers -> global natural.
template<int DIR>
__device__ __forceinline__ void row_fin5_store(const float2* __restrict__ src,
                                               float2* __restrict__ gdst, int tid)
{
    for (int q = tid; q < 384; q += 256) {
        float2 a[5], b[5];
        #pragma unroll
        for (int u = 0; u < 5; ++u) a[u] = src[IDX(q + 384*u)];
        dft5<DIR>(a,b);
        #pragma unroll
        for (int u = 0; u < 5; ++u) gdst[q + 384*u] = b[u];
    }
}

// ---------------- column (1080 = 6*6*6*5, B=2 cols interleaved) pieces ------

// Stage 1, radix-6, S=2, from global; padded rows 270..809 nonzero:
// a1 = g[p-90] (p>=90), a2 = g[p+90], a3 = g[p+270], a4 = g[p+450] (p<90).
__device__ __forceinline__ void col_s1_fwd(const float2* __restrict__ g, int c0,
                                           float2* __restrict__ bA, int tid)
{
    constexpr float STEP = -PI2 / 1080.0f;
    const float2 z = make_float2(0.f,0.f);
    for (int i = tid; i < 360; i += 256) {
        const int p = i >> 1, q = i & 1;
        const float2* gc = g + c0 + q;
        float2 a[6], b[6];
        a[0] = z; a[5] = z;
        a[1] = (p >= 90) ? gc[(p-90)*1920]  : z;
        a[2] = gc[(p+90)*1920];
        a[3] = gc[(p+270)*1920];
        a[4] = (p < 90)  ? gc[(p+450)*1920] : z;
        dft6<-1>(a,b);
        float sv, cv; __sincosf(STEP * (float)p, &sv, &cv);
        float2 w1 = make_float2(cv, sv), w = w1;
        b[1] = cmul(b[1], w);
        #pragma unroll
        for (int u = 2; u < 6; ++u) { w = cmul(w, w1); b[u] = cmul(b[u], w); }
        const int ob = q + 12*p;
        #pragma unroll
        for (int u = 0; u < 6; ++u) bA[IDX(ob + 2*u)] = b[u];
    }
}

// Inverse stage 1, radix-6, with fused K-multiply (reads natural spectrum).
__device__ __forceinline__ void col_s1_inv_mulK(const float2* __restrict__ bSrc,
                                                float2* __restrict__ bDst,
                                                const float2* __restrict__ KT,
                                                int c0, int tid)
{
    constexpr float STEP = PI2 / 1080.0f;
    for (int i = tid; i < 360; i += 256) {
        const int p = i >> 1, q = i & 1;
        const float2* Kc = KT + (c0 + q)*1080 + p;
        float2 a[6], b[6];
        #pragma unroll
        for (int t = 0; t < 6; ++t) a[t] = cmul(bSrc[IDX(i + 360*t)], Kc[180*t]);
        dft6<1>(a,b);
        float sv, cv; __sincosf(STEP * (float)p, &sv, &cv);
        float2 w1 = make_float2(cv, sv), w = w1;
        b[1] = cmul(b[1], w);
        #pragma unroll
        for (int u = 2; u < 6; ++u) { w = cmul(w, w1); b[u] = cmul(b[u], w); }
        const int ob = q + 12*p;
        #pragma unroll
        for (int u = 0; u < 6; ++u) bDst[IDX(ob + 2*u)] = b[u];
    }
}

// Forward final stage, radix-5, S=432, p=0: LDS -> LDS (spectrum for mulK).
template<int DIR>
__device__ __forceinline__ void col_fin5_lds(const float2* __restrict__ src,
                                             float2* __restrict__ dst, int tid)
{
    for (int q = tid; q < 432; q += 256) {
        float2 a[5], b[5];
        #pragma unroll
        for (int u = 0; u < 5; ++u) a[u] = src[IDX(q + 432*u)];
        dft5<DIR>(a,b);
        #pragma unroll
        for (int u = 0; u < 5; ++u) dst[IDX(q + 432*u)] = b[u];
    }
}

// Inverse final stage, radix-5, fused crop (row remap (k+810)%1080) + store.
__device__ __forceinline__ void col_fin5_crop_store(const float2* __restrict__ src,
                                                    float2* __restrict__ Zp,
                                                    int c0, int tid)
{
    for (int q = tid; q < 432; q += 256) {
        float2 a[5], b[5];
        #pragma unroll
        for (int u = 0; u < 5; ++u) a[u] = src[IDX(q + 432*u)];
        dft5<1>(a,b);
        const int qk = q >> 1, c = c0 + (q & 1);
        Zp[(qk + 270)*1920 + c] = b[0];
        if (qk < 54)   Zp[(qk + 486)*1920 + c] = b[1];
        if (qk >= 162) Zp[(qk - 162)*1920 + c] = b[3];
        Zp[(qk + 54)*1920 + c]  = b[4];
    }
}

// ---------------- kernels ----------------

// K1: row FFTs of padded h. Hrow[r][k], r=0..539 = padded row 270+r.
__global__ __launch_bounds__(256,5) void k_row_fft_h(const float* __restrict__ h,
                                                     float2* __restrict__ Hrow)
{
    __shared__ float2 bA[IDXSZ(1920)], bB[IDXSZ(1920)];
    const int tid = threadIdx.x, r = blockIdx.x;
    row_s1_fwd<false>(h + r*960, nullptr, bA, tid); __syncthreads();
    mid_stage<-1,8,240, 8>(bA, bB, tid); __syncthreads();
    mid_stage<-1,6, 30,64>(bB, bA, tid); __syncthreads();
    row_fin5_store<-1>(bA, Hrow + r*1920, tid);
}

// K2: column FFTs of Hrow (2 cols/block) + build KT[c][k] from registers.
// XCD-chunked swizzle: xcd = bid&7 owns columns [xcd*240, xcd*240+240).
__global__ __launch_bounds__(256,4) void k_col_fft_h_buildK(const float2* __restrict__ Hrow,
                                                            const float* __restrict__ mu1,
                                                            float2* __restrict__ KT)
{
    __shared__ float2 bA[IDXSZ(2160)], bB[IDXSZ(2160)];
    const int tid = threadIdx.x;
    const int xcd = blockIdx.x & 7, idx = blockIdx.x >> 3;   // idx in [0,120)
    const int c0 = (xcd*120 + idx)*2;
    col_s1_fwd(Hrow, c0, bA, tid); __syncthreads();
    mid_stage<-1,6,180,12>(bA, bB, tid); __syncthreads();
    mid_stage<-1,6, 30,72>(bB, bA, tid); __syncthreads();
    const float sc = mu1[4] / ((1.0f + 1e-6f) * 2073600.0f);
    for (int q = tid; q < 432; q += 256) {
        float2 a[5], b[5];
        #pragma unroll
        for (int u = 0; u < 5; ++u) a[u] = bA[IDX(q + 432*u)];
        dft5<-1>(a,b);
        const int qk = q >> 1, c = c0 + (q & 1);
        const float cosc = __cosf(PI2 * (float)c * (1.0f/1920.0f));
        #pragma unroll
        for (int u = 0; u < 5; ++u) {
            const int k = qk + 216*u;
            float2 Hv = b[u];
            float mag2 = Hv.x*Hv.x + Hv.y*Hv.y;
            float ps = 4.0f - 2.0f*__cosf(PI2 * (float)k * (1.0f/1080.0f)) - 2.0f*cosc;
            float f = sc / (1e-6f*mag2 + 1e-5f*ps + 4e-5f);
            KT[c*1080 + k] = make_float2(f*Hv.x, -f*Hv.y);
        }
    }
}

// K3: row FFTs of padded x, pairs packed z = x_a + i*x_b.
__global__ __launch_bounds__(256,5) void k_row_fft_x(const float* __restrict__ x,
                                                     float2* __restrict__ Z)
{
    __shared__ float2 bA[IDXSZ(1920)], bB[IDXSZ(1920)];
    const int tid = threadIdx.x;
    const int p = blockIdx.x / 540;
    const int r = blockIdx.x % 540;
    row_s1_fwd<true>(x + ((2*p)*540 + r)*960, x + ((2*p+1)*540 + r)*960, bA, tid);
    __syncthreads();
    mid_stage<-1,8,240, 8>(bA, bB, tid); __syncthreads();
    mid_stage<-1,6, 30,64>(bB, bA, tid); __syncthreads();
    row_fin5_store<-1>(bA, Z + (p*540 + r)*1920, tid);
}

// K4: fused column pass, 2 cols/block, 1 pair/block, grid 3840.
// XCD-chunked swizzle: xcd = bid&7, idx = bid>>3 in [0,480);
// c0 = (xcd*120 + idx%120)*2, pair = idx/120. Each XCD owns a contiguous
// 240-column slab for all 4 pairs -> Z cache-line sharers co-located,
// KT slab (2MB) L2-resident across pairs.
__global__ __launch_bounds__(256,4) void k_col_fused(float2* __restrict__ Z,
                                                     const float2* __restrict__ KT)
{
    __shared__ float2 bA[IDXSZ(2160)], bB[IDXSZ(2160)];
    const int tid = threadIdx.x;
    const int xcd = blockIdx.x & 7, idx = blockIdx.x >> 3;
    const int pp  = idx / 120;
    const int c0  = (xcd*120 + (idx - pp*120))*2;
    float2* Zp = Z + pp*540*1920;
    col_s1_fwd(Zp, c0, bA, tid);          __syncthreads();
    mid_stage<-1,6,180,12>(bA, bB, tid);  __syncthreads();
    mid_stage<-1,6, 30,72>(bB, bA, tid);  __syncthreads();
    col_fin5_lds<-1>(bA, bB, tid);        __syncthreads();
    col_s1_inv_mulK(bB, bA, KT, c0, tid); __syncthreads();
    mid_stage<1,6,180,12>(bA, bB, tid);   __syncthreads();
    mid_stage<1,6, 30,72>(bB, bA, tid);   __syncthreads();
    col_fin5_crop_store(bA, Zp, c0, tid);
}

// K5: row IFFTs + column crop remap + split pair into two real outputs.
__global__ __launch_bounds__(256,5) void k_row_ifft_out(const float2* __restrict__ Z,
                                                        float* __restrict__ out)
{
    __shared__ float2 bA[IDXSZ(1920)], bB[IDXSZ(1920)];
    const int tid = threadIdx.x;
    const int p = blockIdx.x / 540;
    const int r = blockIdx.x % 540;
    row_s1_inv(Z + (p*540 + r)*1920, bA, tid); __syncthreads();
    mid_stage<1,8,240, 8>(bA, bB, tid); __syncthreads();
    mid_stage<1,6, 30,64>(bB, bA, tid); __syncthreads();
    float* oa = out + ((2*p)*540 + r)*960;
    float* ob = out + ((2*p+1)*540 + r)*960;
    for (int q = tid; q < 384; q += 256) {
        float2 a[5], b[5];
        #pragma unroll
        for (int u = 0; u < 5; ++u) a[u] = bA[IDX(q + 384*u)];
        dft5<1>(a,b);
        oa[q+480] = b[0].x; ob[q+480] = b[0].y;
        if (q < 96)   { oa[q+864] = b[1].x; ob[q+864] = b[1].y; }
        if (q >= 288) { oa[q-288] = b[3].x; ob[q-288] = b[3].y; }
        oa[q+96]  = b[4].x; ob[q+96]  = b[4].y;
    }
}

extern "C" void kernel_launch(void* const* d_in, const int* in_sizes, int n_in,
                              void* d_out, int out_size, void* d_ws, size_t ws_size,
                              hipStream_t stream)
{
    (void)in_sizes; (void)n_in; (void)out_size; (void)ws_size;
    const float* x   = (const float*)d_in[0];
    const float* h   = (const float*)d_in[1];
    const float* mu1 = (const float*)d_in[2];
    float*       out = (float*)d_out;

    // ws layout: KT (1080*1920 c64) | Z (4*540*1920 c64); Hrow aliases Z.
    float2* KT   = (float2*)d_ws;
    float2* Z    = KT + 1080*1920;
    float2* Hrow = Z;

    k_row_fft_h       <<<540,    256, 0, stream>>>(h, Hrow);
    k_col_fft_h_buildK<<<960,    256, 0, stream>>>(Hrow, mu1, KT);
    k_row_fft_x       <<<4*540,  256, 0, stream>>>(x, Z);
    k_col_fused       <<<3840,   256, 0, stream>>>(Z, KT);
    k_row_ifft_out    <<<4*540,  256, 0, stream>>>(Z, out);
}

// Round 5
// 99.797 us; speedup vs baseline: 1.6180x; 1.0040x over previous
//
#include <hip/hip_runtime.h>

// Le-ADMM reduction: state resets each iteration => output is one linear
// circular filter: out = crop_shift( IFFT2( K . FFT2(pad(x)) ) ),
// K = mu1[4]/((1+1e-6)*FH*FW) * conj(Hp) / (1e-6|Hp|^2 + 1e-5*PsiTPsi + 4e-5).
// Pairs packed z = x_a + i*x_b (K Hermitian => both results real).
//
// R4: k_col_fused inverse refactored as 1080 = 5*6*6*6 so the forward-final
// radix-5 stage and inverse-first radix-5 stage touch the SAME LDS slots:
// fused into one register pass (dft5 fwd -> *K -> dft5 inv -> twiddle).
// Inverse ends with twiddle-free radix-6 final fused with crop-store.
// Passes 8->7, LDS round-trips 7->6, barriers 7->6, KT pass eliminated.
// Keeps R3's XCD-chunked swizzle (xcd owns a 240-col slab for all 4 pairs).

#define PI2 6.2831853071795864f

__device__ __forceinline__ float2 cadd(float2 a, float2 b){ return make_float2(a.x+b.x, a.y+b.y); }
__device__ __forceinline__ float2 csub(float2 a, float2 b){ return make_float2(a.x-b.x, a.y-b.y); }
__device__ __forceinline__ float2 cmul(float2 a, float2 b){ return make_float2(a.x*b.x - a.y*b.y, a.x*b.y + a.y*b.x); }

// LDS pad: +1 element every 16 to break power-of-2 stride conflicts.
__device__ __forceinline__ int IDX(int a){ return a + (a >> 4); }
#define IDXSZ(n) ((n) + ((n) >> 4))

template<int DIR>
__device__ __forceinline__ void dft3(float2 x0, float2 x1, float2 x2,
                                     float2& y0, float2& y1, float2& y2)
{
    constexpr float s3 = (float)DIR * 0.8660254037844386f;
    float2 t = cadd(x1, x2), u = csub(x1, x2);
    float2 m = make_float2(x0.x - 0.5f*t.x, x0.y - 0.5f*t.y);
    float2 iu = make_float2(-s3*u.y, s3*u.x);
    y0 = cadd(x0, t); y1 = cadd(m, iu); y2 = csub(m, iu);
}

template<int DIR>
__device__ __forceinline__ void dft4(float2 a0, float2 a1, float2 a2, float2 a3,
                                     float2& b0, float2& b1, float2& b2, float2& b3)
{
    float2 t0 = cadd(a0,a2), t1 = csub(a0,a2), t2 = cadd(a1,a3), t3 = csub(a1,a3);
    float2 j3 = make_float2(-(float)DIR*t3.y, (float)DIR*t3.x);
    b0 = cadd(t0,t2); b2 = csub(t0,t2); b1 = cadd(t1,j3); b3 = csub(t1,j3);
}

template<int DIR>
__device__ __forceinline__ void dft6(const float2 a[6], float2 b[6])
{
    float2 e0,e1,e2,o0,o1,o2;
    dft3<DIR>(a[0],a[2],a[4], e0,e1,e2);
    dft3<DIR>(a[1],a[3],a[5], o0,o1,o2);
    constexpr float s3 = (float)DIR * 0.8660254037844386f;
    float2 w1 = make_float2( 0.5f, s3);   // exp(DIR*i*pi/3)
    float2 w2 = make_float2(-0.5f, s3);
    float2 t1 = cmul(w1,o1), t2 = cmul(w2,o2);
    b[0]=cadd(e0,o0); b[3]=csub(e0,o0);
    b[1]=cadd(e1,t1); b[4]=csub(e1,t1);
    b[2]=cadd(e2,t2); b[5]=csub(e2,t2);
}

template<int DIR>
__device__ __forceinline__ void dft8(const float2 a[8], float2 b[8])
{
    float2 e0,e1,e2,e3,o0,o1,o2,o3;
    dft4<DIR>(a[0],a[2],a[4],a[6], e0,e1,e2,e3);
    dft4<DIR>(a[1],a[3],a[5],a[7], o0,o1,o2,o3);
    constexpr float c = 0.70710678118654752f;
    float2 w1 = make_float2( c, (float)DIR*c);
    float2 w3 = make_float2(-c, (float)DIR*c);
    float2 t1 = cmul(w1,o1);
    float2 t2 = make_float2(-(float)DIR*o2.y, (float)DIR*o2.x);
    float2 t3 = cmul(w3,o3);
    b[0]=cadd(e0,o0); b[4]=csub(e0,o0);
    b[1]=cadd(e1,t1); b[5]=csub(e1,t1);
    b[2]=cadd(e2,t2); b[6]=csub(e2,t2);
    b[3]=cadd(e3,t3); b[7]=csub(e3,t3);
}

template<int DIR>
__device__ __forceinline__ void dft5(const float2 a[5], float2 b[5])
{
    constexpr float C1 = 0.30901699437494742f, S1c = 0.9510565162951535f;
    constexpr float C2 = -0.8090169943749475f, S2c = 0.5877852522924731f;
    float2 t1 = cadd(a[1],a[4]), t2 = cadd(a[2],a[3]), d1 = csub(a[1],a[4]), d2 = csub(a[2],a[3]);
    float2 m1 = make_float2(a[0].x + C1*t1.x + C2*t2.x, a[0].y + C1*t1.y + C2*t2.y);
    float2 m2 = make_float2(a[0].x + C2*t1.x + C1*t2.x, a[0].y + C2*t1.y + C1*t2.y);
    float2 e1 = make_float2(S1c*d1.x + S2c*d2.x, S1c*d1.y + S2c*d2.y);
    float2 e2 = make_float2(S2c*d1.x - S1c*d2.x, S2c*d1.y - S1c*d2.y);
    float2 ie1 = make_float2(-(float)DIR*e1.y, (float)DIR*e1.x);
    float2 ie2 = make_float2(-(float)DIR*e2.y, (float)DIR*e2.x);
    b[0] = make_float2(a[0].x + t1.x + t2.x, a[0].y + t1.y + t2.y);
    b[1] = cadd(m1, ie1); b[4] = csub(m1, ie1);
    b[2] = cadd(m2, ie2); b[3] = csub(m2, ie2);
}

// Generic middle Stockham stage (R = 6 or 8), LDS -> LDS.
template<int DIR, int R, int NCUR, int S>
__device__ __forceinline__ void mid_stage(const float2* __restrict__ src,
                                          float2* __restrict__ dst, int tid)
{
    constexpr int M  = NCUR / R;
    constexpr int NB = M * S;
    constexpr float STEP = (float)DIR * PI2 / (float)NCUR;
    for (int i = tid; i < NB; i += 256) {
        const int p = i / S;
        float2 a[R], b[R];
        #pragma unroll
        for (int t = 0; t < R; ++t) a[t] = src[IDX(i + S*M*t)];
        if constexpr (R == 6) dft6<DIR>(a,b); else dft8<DIR>(a,b);
        float sv, cv; __sincosf(STEP * (float)p, &sv, &cv);
        float2 w1 = make_float2(cv, sv), w = w1;
        b[1] = cmul(b[1], w);
        #pragma unroll
        for (int u = 2; u < R; ++u) { w = cmul(w, w1); b[u] = cmul(b[u], w); }
        const int ob = (i - p*S) + S*(R*p);
        #pragma unroll
        for (int u = 0; u < R; ++u) dst[IDX(ob + S*u)] = b[u];
    }
}

// ---------------- row (1920 = 8*8*6*5) pieces ----------------

// Stage 1, radix-8, S=1, from global; padded cols 480..1439 nonzero
// => a[2..5] = x[p], x[p+240], x[p+480], x[p+720]; rest 0.
template<bool HASB>
__device__ __forceinline__ void row_s1_fwd(const float* __restrict__ xa,
                                           const float* __restrict__ xb,
                                           float2* __restrict__ bA, int tid)
{
    constexpr float STEP = -PI2 / 1920.0f;
    const float2 z = make_float2(0.f,0.f);
    for (int p = tid; p < 240; p += 256) {
        float2 a[8], b[8];
        a[0]=z; a[1]=z; a[6]=z; a[7]=z;
        a[2] = make_float2(xa[p],     HASB ? xb[p]     : 0.f);
        a[3] = make_float2(xa[p+240], HASB ? xb[p+240] : 0.f);
        a[4] = make_float2(xa[p+480], HASB ? xb[p+480] : 0.f);
        a[5] = make_float2(xa[p+720], HASB ? xb[p+720] : 0.f);
        dft8<-1>(a,b);
        float sv, cv; __sincosf(STEP * (float)p, &sv, &cv);
        float2 w1 = make_float2(cv, sv), w = w1;
        b[1] = cmul(b[1], w);
        #pragma unroll
        for (int u = 2; u < 8; ++u) { w = cmul(w, w1); b[u] = cmul(b[u], w); }
        #pragma unroll
        for (int u = 0; u < 8; ++u) bA[IDX(8*p + u)] = b[u];
    }
}

// Stage 1, radix-8, S=1, inverse, full read from global spectrum.
__device__ __forceinline__ void row_s1_inv(const float2* __restrict__ Zp,
                                           float2* __restrict__ bA, int tid)
{
    constexpr float STEP = PI2 / 1920.0f;
    for (int p = tid; p < 240; p += 256) {
        float2 a[8], b[8];
        #pragma unroll
        for (int t = 0; t < 8; ++t) a[t] = Zp[p + 240*t];
        dft8<1>(a,b);
        float sv, cv; __sincosf(STEP * (float)p, &sv, &cv);
        float2 w1 = make_float2(cv, sv), w = w1;
        b[1] = cmul(b[1], w);
        #pragma unroll
        for (int u = 2; u < 8; ++u) { w = cmul(w, w1); b[u] = cmul(b[u], w); }
        #pragma unroll
        for (int u = 0; u < 8; ++u) bA[IDX(8*p + u)] = b[u];
    }
}

// Final stage, radix-5, S=384, p=0 (no twiddle): registers -> global natural.
template<int DIR>
__device__ __forceinline__ void row_fin5_store(const float2* __restrict__ src,
                                               float2* __restrict__ gdst, int tid)
{
    for (int q = tid; q < 384; q += 256) {
        float2 a[5], b[5];
        #pragma unroll
        for (int u = 0; u < 5; ++u) a[u] = src[IDX(q + 384*u)];
        dft5<DIR>(a,b);
        #pragma unroll
        for (int u = 0; u < 5; ++u) gdst[q + 384*u] = b[u];
    }
}

// ---------------- column (fwd 1080 = 6*6*6*5, inv 1080 = 5*6*6*6) ----------
// B=2 columns interleaved: LDS idx = (col&1) + 2*(per-column position).

// Stage 1, radix-6, S=2, from global; padded rows 270..809 nonzero:
// a1 = g[p-90] (p>=90), a2 = g[p+90], a3 = g[p+270], a4 = g[p+450] (p<90).
__device__ __forceinline__ void col_s1_fwd(const float2* __restrict__ g, int c0,
                                           float2* __restrict__ bA, int tid)
{
    constexpr float STEP = -PI2 / 1080.0f;
    const float2 z = make_float2(0.f,0.f);
    for (int i = tid; i < 360; i += 256) {
        const int p = i >> 1, q = i & 1;
        const float2* gc = g + c0 + q;
        float2 a[6], b[6];
        a[0] = z; a[5] = z;
        a[1] = (p >= 90) ? gc[(p-90)*1920]  : z;
        a[2] = gc[(p+90)*1920];
        a[3] = gc[(p+270)*1920];
        a[4] = (p < 90)  ? gc[(p+450)*1920] : z;
        dft6<-1>(a,b);
        float sv, cv; __sincosf(STEP * (float)p, &sv, &cv);
        float2 w1 = make_float2(cv, sv), w = w1;
        b[1] = cmul(b[1], w);
        #pragma unroll
        for (int u = 2; u < 6; ++u) { w = cmul(w, w1); b[u] = cmul(b[u], w); }
        const int ob = q + 12*p;
        #pragma unroll
        for (int u = 0; u < 6; ++u) bA[IDX(ob + 2*u)] = b[u];
    }
}

// Fused: forward-final radix-5 (p=0, twiddle-free -> natural spectrum
// k = p + 216u) -> multiply by KT[c][k] -> inverse-first radix-5
// (NCUR=1080, S=2, twiddle exp(+2pi i p u/1080)) -> Stockham scatter.
// Both radix-5 stages touch the SAME LDS slots i + 432u: one register pass.
__device__ __forceinline__ void col_fused5K5(const float2* __restrict__ src,
                                             float2* __restrict__ dst,
                                             const float2* __restrict__ KT,
                                             int c0, int tid)
{
    constexpr float STEP = PI2 / 1080.0f;
    for (int i = tid; i < 432; i += 256) {
        const int p = i >> 1, q0 = i & 1;
        const float2* Kc = KT + (c0 + q0)*1080 + p;
        float2 a[5], s[5], d[5];
        #pragma unroll
        for (int u = 0; u < 5; ++u) a[u] = src[IDX(i + 432*u)];
        dft5<-1>(a, s);                        // natural spectrum k = p+216u
        #pragma unroll
        for (int u = 0; u < 5; ++u) s[u] = cmul(s[u], Kc[216*u]);
        dft5<1>(s, d);                         // inverse stage 1
        float sv, cv; __sincosf(STEP * (float)p, &sv, &cv);
        float2 w1 = make_float2(cv, sv), w = w1;
        d[1] = cmul(d[1], w);
        #pragma unroll
        for (int u = 2; u < 5; ++u) { w = cmul(w, w1); d[u] = cmul(d[u], w); }
        const int ob = q0 + 10*p;              // q + S*R*p, S=2, R=5
        #pragma unroll
        for (int u = 0; u < 5; ++u) dst[IDX(ob + 2*u)] = d[u];
    }
}

// Inverse final radix-6 (NCUR=6, S=360, p=0, twiddle-free) fused with crop:
// per-column output n = m + 180u; needed n in [0,270) -> ir=n+270 and
// [810,1080) -> ir=n-810. u=0 all, u=1 if m<90, u=4 if m>=90, u=5 all.
__device__ __forceinline__ void col_fin6_crop_store(const float2* __restrict__ src,
                                                    float2* __restrict__ Zp,
                                                    int c0, int tid)
{
    for (int i = tid; i < 360; i += 256) {
        float2 a[6], b[6];
        #pragma unroll
        for (int t = 0; t < 6; ++t) a[t] = src[IDX(i + 360*t)];
        dft6<1>(a,b);
        const int m = i >> 1, c = c0 + (i & 1);
        Zp[(m + 270)*1920 + c] = b[0];
        if (m < 90)  Zp[(m + 450)*1920 + c] = b[1];
        if (m >= 90) Zp[(m - 90)*1920 + c]  = b[4];
        Zp[(m + 90)*1920 + c]  = b[5];
    }
}

// ---------------- kernels ----------------

// K1: row FFTs of padded h. Hrow[r][k], r=0..539 = padded row 270+r.
__global__ __launch_bounds__(256,5) void k_row_fft_h(const float* __restrict__ h,
                                                     float2* __restrict__ Hrow)
{
    __shared__ float2 bA[IDXSZ(1920)], bB[IDXSZ(1920)];
    const int tid = threadIdx.x, r = blockIdx.x;
    row_s1_fwd<false>(h + r*960, nullptr, bA, tid); __syncthreads();
    mid_stage<-1,8,240, 8>(bA, bB, tid); __syncthreads();
    mid_stage<-1,6, 30,64>(bB, bA, tid); __syncthreads();
    row_fin5_store<-1>(bA, Hrow + r*1920, tid);
}

// K2: column FFTs of Hrow (2 cols/block) + build KT[c][k] from registers.
// XCD-chunked swizzle: xcd = bid&7 owns columns [xcd*240, xcd*240+240).
__global__ __launch_bounds__(256,4) void k_col_fft_h_buildK(const float2* __restrict__ Hrow,
                                                            const float* __restrict__ mu1,
                                                            float2* __restrict__ KT)
{
    __shared__ float2 bA[IDXSZ(2160)], bB[IDXSZ(2160)];
    const int tid = threadIdx.x;
    const int xcd = blockIdx.x & 7, idx = blockIdx.x >> 3;   // idx in [0,120)
    const int c0 = (xcd*120 + idx)*2;
    col_s1_fwd(Hrow, c0, bA, tid); __syncthreads();
    mid_stage<-1,6,180,12>(bA, bB, tid); __syncthreads();
    mid_stage<-1,6, 30,72>(bB, bA, tid); __syncthreads();
    const float sc = mu1[4] / ((1.0f + 1e-6f) * 2073600.0f);
    for (int q = tid; q < 432; q += 256) {
        float2 a[5], b[5];
        #pragma unroll
        for (int u = 0; u < 5; ++u) a[u] = bA[IDX(q + 432*u)];
        dft5<-1>(a,b);
        const int qk = q >> 1, c = c0 + (q & 1);
        const float cosc = __cosf(PI2 * (float)c * (1.0f/1920.0f));
        #pragma unroll
        for (int u = 0; u < 5; ++u) {
            const int k = qk + 216*u;
            float2 Hv = b[u];
            float mag2 = Hv.x*Hv.x + Hv.y*Hv.y;
            float ps = 4.0f - 2.0f*__cosf(PI2 * (float)k * (1.0f/1080.0f)) - 2.0f*cosc;
            float f = sc / (1e-6f*mag2 + 1e-5f*ps + 4e-5f);
            KT[c*1080 + k] = make_float2(f*Hv.x, -f*Hv.y);
        }
    }
}

// K3: row FFTs of padded x, pairs packed z = x_a + i*x_b.
__global__ __launch_bounds__(256,5) void k_row_fft_x(const float* __restrict__ x,
                                                     float2* __restrict__ Z)
{
    __shared__ float2 bA[IDXSZ(1920)], bB[IDXSZ(1920)];
    const int tid = threadIdx.x;
    const int p = blockIdx.x / 540;
    const int r = blockIdx.x % 540;
    row_s1_fwd<true>(x + ((2*p)*540 + r)*960, x + ((2*p+1)*540 + r)*960, bA, tid);
    __syncthreads();
    mid_stage<-1,8,240, 8>(bA, bB, tid); __syncthreads();
    mid_stage<-1,6, 30,64>(bB, bA, tid); __syncthreads();
    row_fin5_store<-1>(bA, Z + (p*540 + r)*1920, tid);
}

// K4: fused column pass, 2 cols/block, 1 pair/block, grid 3840.
// fwd (6,6,6,[5) fused K (5],6,6,6) inv; 7 passes, 6 barriers.
// XCD-chunked swizzle: xcd = bid&7, idx = bid>>3 in [0,480);
// c0 = (xcd*120 + idx%120)*2, pair = idx/120.
__global__ __launch_bounds__(256,4) void k_col_fused(float2* __restrict__ Z,
                                                     const float2* __restrict__ KT)
{
    __shared__ float2 bA[IDXSZ(2160)], bB[IDXSZ(2160)];
    const int tid = threadIdx.x;
    const int xcd = blockIdx.x & 7, idx = blockIdx.x >> 3;
    const int pp  = idx / 120;
    const int c0  = (xcd*120 + (idx - pp*120))*2;
    float2* Zp = Z + pp*540*1920;
    col_s1_fwd(Zp, c0, bA, tid);          __syncthreads();
    mid_stage<-1,6,180,12>(bA, bB, tid);  __syncthreads();
    mid_stage<-1,6, 30,72>(bB, bA, tid);  __syncthreads();
    col_fused5K5(bA, bB, KT, c0, tid);    __syncthreads();
    mid_stage<1,6,216,10>(bB, bA, tid);   __syncthreads();
    mid_stage<1,6, 36,60>(bA, bB, tid);   __syncthreads();
    col_fin6_crop_store(bB, Zp, c0, tid);
}

// K5: row IFFTs + column crop remap + split pair into two real outputs.
__global__ __launch_bounds__(256,5) void k_row_ifft_out(const float2* __restrict__ Z,
                                                        float* __restrict__ out)
{
    __shared__ float2 bA[IDXSZ(1920)], bB[IDXSZ(1920)];
    const int tid = threadIdx.x;
    const int p = blockIdx.x / 540;
    const int r = blockIdx.x % 540;
    row_s1_inv(Z + (p*540 + r)*1920, bA, tid); __syncthreads();
    mid_stage<1,8,240, 8>(bA, bB, tid); __syncthreads();
    mid_stage<1,6, 30,64>(bB, bA, tid); __syncthreads();
    float* oa = out + ((2*p)*540 + r)*960;
    float* ob = out + ((2*p+1)*540 + r)*960;
    for (int q = tid; q < 384; q += 256) {
        float2 a[5], b[5];
        #pragma unroll
        for (int u = 0; u < 5; ++u) a[u] = bA[IDX(q + 384*u)];
        dft5<1>(a,b);
        oa[q+480] = b[0].x; ob[q+480] = b[0].y;
        if (q < 96)   { oa[q+864] = b[1].x; ob[q+864] = b[1].y; }
        if (q >= 288) { oa[q-288] = b[3].x; ob[q-288] = b[3].y; }
        oa[q+96]  = b[4].x; ob[q+96]  = b[4].y;
    }
}

extern "C" void kernel_launch(void* const* d_in, const int* in_sizes, int n_in,
                              void* d_out, int out_size, void* d_ws, size_t ws_size,
                              hipStream_t stream)
{
    (void)in_sizes; (void)n_in; (void)out_size; (void)ws_size;
    const float* x   = (const float*)d_in[0];
    const float* h   = (const float*)d_in[1];
    const float* mu1 = (const float*)d_in[2];
    float*       out = (float*)d_out;

    // ws layout: KT (1080*1920 c64) | Z (4*540*1920 c64); Hrow aliases Z.
    float2* KT   = (float2*)d_ws;
    float2* Z    = KT + 1080*1920;
    float2* Hrow = Z;

    k_row_fft_h       <<<540,    256, 0, stream>>>(h, Hrow);
    k_col_fft_h_buildK<<<960,    256, 0, stream>>>(Hrow, mu1, KT);
    k_row_fft_x       <<<4*540,  256, 0, stream>>>(x, Z);
    k_col_fused       <<<3840,   256, 0, stream>>>(Z, KT);
    k_row_ifft_out    <<<4*540,  256, 0, stream>>>(Z, out);
}

// Round 6
// 87.182 us; speedup vs baseline: 1.8521x; 1.1447x over previous
//
#include <hip/hip_runtime.h>

// Le-ADMM reduction: state resets each iteration => output is one linear
// circular filter: out = crop_shift( IFFT2( K . FFT2(pad(x)) ) ),
// K = mu1[4]/((1+1e-6)*FH*FW) * conj(Hp) / (1e-6|Hp|^2 + 1e-5*PsiTPsi + 4e-5).
// Pairs packed z = x_a + i*x_b (K Hermitian => both results real).
//
// R5: column kernels restructured so ONE THREAD owns BOTH interleaved
// columns at the same per-column position: float4 (b128) LDS ops (half the
// LDS instruction count), one shared sincos+twiddle chain per butterfly-pair,
// float4 global load/store, KT re-laid out pair-interleaved for float4 K
// loads. LDS padding +2 per 32 slots (keeps float4 alignment).
// Keeps: R3 XCD-chunked swizzle; R4 fused 5-K-5 center pass (fwd 6,6,6,[5 x
// K 5],6,6,6 inv); stage-1 from global; final stage fused with crop-store.

#define PI2 6.2831853071795864f

__device__ __forceinline__ float2 cadd(float2 a, float2 b){ return make_float2(a.x+b.x, a.y+b.y); }
__device__ __forceinline__ float2 csub(float2 a, float2 b){ return make_float2(a.x-b.x, a.y-b.y); }
__device__ __forceinline__ float2 cmul(float2 a, float2 b){ return make_float2(a.x*b.x - a.y*b.y, a.x*b.y + a.y*b.x); }
__device__ __forceinline__ float4 pk(float2 a, float2 b){ return make_float4(a.x,a.y,b.x,b.y); }

// Row kernels: pad +1 per 16 (b64 access).
__device__ __forceinline__ int IDX(int a){ return a + (a >> 4); }
#define IDXSZ(n) ((n) + ((n) >> 4))
// Column kernels: pad +2 per 32 (keeps even->even so float4 stays aligned).
__device__ __forceinline__ int IDXP(int a){ return a + ((a >> 5) << 1); }
#define IDXPSZ(n) ((n) + (((n) >> 5) << 1) + 4)

// Pair load/store: both columns at per-col position pos (slots 2*pos, 2*pos+1).
__device__ __forceinline__ void ldp(const float2* __restrict__ b, int pos,
                                    float2& v0, float2& v1){
    const float4 t = *(const float4*)&b[IDXP(2*pos)];
    v0 = make_float2(t.x,t.y); v1 = make_float2(t.z,t.w);
}
__device__ __forceinline__ void stp(float2* __restrict__ b, int pos,
                                    float2 v0, float2 v1){
    *(float4*)&b[IDXP(2*pos)] = pk(v0, v1);
}

template<int DIR>
__device__ __forceinline__ void dft3(float2 x0, float2 x1, float2 x2,
                                     float2& y0, float2& y1, float2& y2)
{
    constexpr float s3 = (float)DIR * 0.8660254037844386f;
    float2 t = cadd(x1, x2), u = csub(x1, x2);
    float2 m = make_float2(x0.x - 0.5f*t.x, x0.y - 0.5f*t.y);
    float2 iu = make_float2(-s3*u.y, s3*u.x);
    y0 = cadd(x0, t); y1 = cadd(m, iu); y2 = csub(m, iu);
}

template<int DIR>
__device__ __forceinline__ void dft4(float2 a0, float2 a1, float2 a2, float2 a3,
                                     float2& b0, float2& b1, float2& b2, float2& b3)
{
    float2 t0 = cadd(a0,a2), t1 = csub(a0,a2), t2 = cadd(a1,a3), t3 = csub(a1,a3);
    float2 j3 = make_float2(-(float)DIR*t3.y, (float)DIR*t3.x);
    b0 = cadd(t0,t2); b2 = csub(t0,t2); b1 = cadd(t1,j3); b3 = csub(t1,j3);
}

template<int DIR>
__device__ __forceinline__ void dft6(const float2 a[6], float2 b[6])
{
    float2 e0,e1,e2,o0,o1,o2;
    dft3<DIR>(a[0],a[2],a[4], e0,e1,e2);
    dft3<DIR>(a[1],a[3],a[5], o0,o1,o2);
    constexpr float s3 = (float)DIR * 0.8660254037844386f;
    float2 w1 = make_float2( 0.5f, s3);   // exp(DIR*i*pi/3)
    float2 w2 = make_float2(-0.5f, s3);
    float2 t1 = cmul(w1,o1), t2 = cmul(w2,o2);
    b[0]=cadd(e0,o0); b[3]=csub(e0,o0);
    b[1]=cadd(e1,t1); b[4]=csub(e1,t1);
    b[2]=cadd(e2,t2); b[5]=csub(e2,t2);
}

template<int DIR>
__device__ __forceinline__ void dft8(const float2 a[8], float2 b[8])
{
    float2 e0,e1,e2,e3,o0,o1,o2,o3;
    dft4<DIR>(a[0],a[2],a[4],a[6], e0,e1,e2,e3);
    dft4<DIR>(a[1],a[3],a[5],a[7], o0,o1,o2,o3);
    constexpr float c = 0.70710678118654752f;
    float2 w1 = make_float2( c, (float)DIR*c);
    float2 w3 = make_float2(-c, (float)DIR*c);
    float2 t1 = cmul(w1,o1);
    float2 t2 = make_float2(-(float)DIR*o2.y, (float)DIR*o2.x);
    float2 t3 = cmul(w3,o3);
    b[0]=cadd(e0,o0); b[4]=csub(e0,o0);
    b[1]=cadd(e1,t1); b[5]=csub(e1,t1);
    b[2]=cadd(e2,t2); b[6]=csub(e2,t2);
    b[3]=cadd(e3,t3); b[7]=csub(e3,t3);
}

template<int DIR>
__device__ __forceinline__ void dft5(const float2 a[5], float2 b[5])
{
    constexpr float C1 = 0.30901699437494742f, S1c = 0.9510565162951535f;
    constexpr float C2 = -0.8090169943749475f, S2c = 0.5877852522924731f;
    float2 t1 = cadd(a[1],a[4]), t2 = cadd(a[2],a[3]), d1 = csub(a[1],a[4]), d2 = csub(a[2],a[3]);
    float2 m1 = make_float2(a[0].x + C1*t1.x + C2*t2.x, a[0].y + C1*t1.y + C2*t2.y);
    float2 m2 = make_float2(a[0].x + C2*t1.x + C1*t2.x, a[0].y + C2*t1.y + C1*t2.y);
    float2 e1 = make_float2(S1c*d1.x + S2c*d2.x, S1c*d1.y + S2c*d2.y);
    float2 e2 = make_float2(S2c*d1.x - S1c*d2.x, S2c*d1.y - S1c*d2.y);
    float2 ie1 = make_float2(-(float)DIR*e1.y, (float)DIR*e1.x);
    float2 ie2 = make_float2(-(float)DIR*e2.y, (float)DIR*e2.x);
    b[0] = make_float2(a[0].x + t1.x + t2.x, a[0].y + t1.y + t2.y);
    b[1] = cadd(m1, ie1); b[4] = csub(m1, ie1);
    b[2] = cadd(m2, ie2); b[3] = csub(m2, ie2);
}

// Generic middle Stockham stage (rows; R = 6 or 8), LDS -> LDS, b64 slots.
template<int DIR, int R, int NCUR, int S>
__device__ __forceinline__ void mid_stage(const float2* __restrict__ src,
                                          float2* __restrict__ dst, int tid)
{
    constexpr int M  = NCUR / R;
    constexpr int NB = M * S;
    constexpr float STEP = (float)DIR * PI2 / (float)NCUR;
    for (int i = tid; i < NB; i += 256) {
        const int p = i / S;
        float2 a[R], b[R];
        #pragma unroll
        for (int t = 0; t < R; ++t) a[t] = src[IDX(i + S*M*t)];
        if constexpr (R == 6) dft6<DIR>(a,b); else dft8<DIR>(a,b);
        float sv, cv; __sincosf(STEP * (float)p, &sv, &cv);
        float2 w1 = make_float2(cv, sv), w = w1;
        b[1] = cmul(b[1], w);
        #pragma unroll
        for (int u = 2; u < R; ++u) { w = cmul(w, w1); b[u] = cmul(b[u], w); }
        const int ob = (i - p*S) + S*(R*p);
        #pragma unroll
        for (int u = 0; u < R; ++u) dst[IDX(ob + S*u)] = b[u];
    }
}

// Column middle stage, pair-per-thread (R=6). SC = per-column done-stride.
template<int DIR, int NCUR, int SC>
__device__ __forceinline__ void mid_pair(const float2* __restrict__ src,
                                         float2* __restrict__ dst, int tid)
{
    constexpr int NB = 180;   // 1080/6 butterflies per column
    constexpr float STEP = (float)DIR * PI2 / (float)NCUR;
    for (int ic = tid; ic < NB; ic += 256) {
        const int p = ic / SC;
        float2 a0[6], a1[6], b0[6], b1[6];
        #pragma unroll
        for (int t = 0; t < 6; ++t) ldp(src, ic + NB*t, a0[t], a1[t]);
        dft6<DIR>(a0,b0); dft6<DIR>(a1,b1);
        float sv, cv; __sincosf(STEP*(float)p, &sv, &cv);
        float2 w1 = make_float2(cv,sv), w = w1;
        b0[1]=cmul(b0[1],w); b1[1]=cmul(b1[1],w);
        #pragma unroll
        for (int u = 2; u < 6; ++u){ w = cmul(w,w1); b0[u]=cmul(b0[u],w); b1[u]=cmul(b1[u],w); }
        const int ob = (ic - p*SC) + SC*6*p;
        #pragma unroll
        for (int u = 0; u < 6; ++u) stp(dst, ob + SC*u, b0[u], b1[u]);
    }
}

// Column stage 1 (radix-6, SC=1, DIR=-1) from global, pair-per-thread,
// zero-pad: padded rows 270..809 nonzero -> a1=g[p-90](p>=90), a2=g[p+90],
// a3=g[p+270], a4=g[p+450](p<90); a0=a5=0. Global float4 (both cols).
__device__ __forceinline__ void col_s1_fwd_pair(const float2* __restrict__ g, int c0,
                                                float2* __restrict__ bA, int tid)
{
    constexpr float STEP = -PI2 / 1080.0f;
    const float2 z = make_float2(0.f,0.f);
    const float4* gc = (const float4*)(g + c0);  // row stride 960 float4
    for (int p = tid; p < 180; p += 256) {
        float2 a0[6], a1[6], b0[6], b1[6];
        a0[0]=a0[5]=a1[0]=a1[5]=z;
        if (p >= 90) { float4 t = gc[(p-90)*960]; a0[1]=make_float2(t.x,t.y); a1[1]=make_float2(t.z,t.w); }
        else         { a0[1]=a1[1]=z; }
        { float4 t = gc[(p+90)*960];  a0[2]=make_float2(t.x,t.y); a1[2]=make_float2(t.z,t.w); }
        { float4 t = gc[(p+270)*960]; a0[3]=make_float2(t.x,t.y); a1[3]=make_float2(t.z,t.w); }
        if (p < 90)  { float4 t = gc[(p+450)*960]; a0[4]=make_float2(t.x,t.y); a1[4]=make_float2(t.z,t.w); }
        else         { a0[4]=a1[4]=z; }
        dft6<-1>(a0,b0); dft6<-1>(a1,b1);
        float sv, cv; __sincosf(STEP*(float)p, &sv, &cv);
        float2 w1 = make_float2(cv,sv), w = w1;
        b0[1]=cmul(b0[1],w); b1[1]=cmul(b1[1],w);
        #pragma unroll
        for (int u = 2; u < 6; ++u){ w = cmul(w,w1); b0[u]=cmul(b0[u],w); b1[u]=cmul(b1[u],w); }
        #pragma unroll
        for (int u = 0; u < 6; ++u) stp(bA, 6*p + u, b0[u], b1[u]);
    }
}

// Fused center: fwd-final radix-5 (p in [0,216), twiddle-free, spectrum
// k = p+216u) -> *K (pair-interleaved KI) -> inverse-first radix-5
// (SC=1, twiddle exp(+2pi i p u/1080)) -> scatter to colpos 5p+u.
__device__ __forceinline__ void fused5K5_pair(const float2* __restrict__ src,
                                              float2* __restrict__ dst,
                                              const float4* __restrict__ KI,
                                              int cpair, int tid)
{
    constexpr float STEP = PI2 / 1080.0f;
    const float4* Kc = KI + cpair*1080;
    for (int p = tid; p < 216; p += 256) {
        float2 a0[5],a1[5],s0[5],s1[5],d0[5],d1[5];
        #pragma unroll
        for (int u = 0; u < 5; ++u) ldp(src, p + 216*u, a0[u], a1[u]);
        dft5<-1>(a0,s0); dft5<-1>(a1,s1);
        #pragma unroll
        for (int u = 0; u < 5; ++u) {
            float4 kk = Kc[p + 216*u];
            s0[u] = cmul(s0[u], make_float2(kk.x,kk.y));
            s1[u] = cmul(s1[u], make_float2(kk.z,kk.w));
        }
        dft5<1>(s0,d0); dft5<1>(s1,d1);
        float sv, cv; __sincosf(STEP*(float)p, &sv, &cv);
        float2 w1 = make_float2(cv,sv), w = w1;
        d0[1]=cmul(d0[1],w); d1[1]=cmul(d1[1],w);
        #pragma unroll
        for (int u = 2; u < 5; ++u){ w = cmul(w,w1); d0[u]=cmul(d0[u],w); d1[u]=cmul(d1[u],w); }
        #pragma unroll
        for (int u = 0; u < 5; ++u) stp(dst, 5*p + u, d0[u], d1[u]);
    }
}

// Inverse final radix-6 (SC=180, p=0, twiddle-free) fused with crop:
// output n = m + 180u; kept: u=0 (ir=n+270), u=1 if m<90, u=4 if m>=90,
// u=5 (ir=n-810). Global float4 stores (both cols).
__device__ __forceinline__ void fin6_crop_pair(const float2* __restrict__ src,
                                               float2* __restrict__ Zp,
                                               int c0, int tid)
{
    float4* gc = (float4*)(Zp + c0);
    for (int m = tid; m < 180; m += 256) {
        float2 a0[6],a1[6],b0[6],b1[6];
        #pragma unroll
        for (int t = 0; t < 6; ++t) ldp(src, m + 180*t, a0[t], a1[t]);
        dft6<1>(a0,b0); dft6<1>(a1,b1);
        gc[(m+270)*960] = pk(b0[0], b1[0]);
        if (m < 90)  gc[(m+450)*960] = pk(b0[1], b1[1]);
        if (m >= 90) gc[(m-90)*960]  = pk(b0[4], b1[4]);
        gc[(m+90)*960]  = pk(b0[5], b1[5]);
    }
}

// ---------------- row (1920 = 8*8*6*5) pieces (unchanged) ----------------

template<bool HASB>
__device__ __forceinline__ void row_s1_fwd(const float* __restrict__ xa,
                                           const float* __restrict__ xb,
                                           float2* __restrict__ bA, int tid)
{
    constexpr float STEP = -PI2 / 1920.0f;
    const float2 z = make_float2(0.f,0.f);
    for (int p = tid; p < 240; p += 256) {
        float2 a[8], b[8];
        a[0]=z; a[1]=z; a[6]=z; a[7]=z;
        a[2] = make_float2(xa[p],     HASB ? xb[p]     : 0.f);
        a[3] = make_float2(xa[p+240], HASB ? xb[p+240] : 0.f);
        a[4] = make_float2(xa[p+480], HASB ? xb[p+480] : 0.f);
        a[5] = make_float2(xa[p+720], HASB ? xb[p+720] : 0.f);
        dft8<-1>(a,b);
        float sv, cv; __sincosf(STEP * (float)p, &sv, &cv);
        float2 w1 = make_float2(cv, sv), w = w1;
        b[1] = cmul(b[1], w);
        #pragma unroll
        for (int u = 2; u < 8; ++u) { w = cmul(w, w1); b[u] = cmul(b[u], w); }
        #pragma unroll
        for (int u = 0; u < 8; ++u) bA[IDX(8*p + u)] = b[u];
    }
}

__device__ __forceinline__ void row_s1_inv(const float2* __restrict__ Zp,
                                           float2* __restrict__ bA, int tid)
{
    constexpr float STEP = PI2 / 1920.0f;
    for (int p = tid; p < 240; p += 256) {
        float2 a[8], b[8];
        #pragma unroll
        for (int t = 0; t < 8; ++t) a[t] = Zp[p + 240*t];
        dft8<1>(a,b);
        float sv, cv; __sincosf(STEP * (float)p, &sv, &cv);
        float2 w1 = make_float2(cv, sv), w = w1;
        b[1] = cmul(b[1], w);
        #pragma unroll
        for (int u = 2; u < 8; ++u) { w = cmul(w, w1); b[u] = cmul(b[u], w); }
        #pragma unroll
        for (int u = 0; u < 8; ++u) bA[IDX(8*p + u)] = b[u];
    }
}

template<int DIR>
__device__ __forceinline__ void row_fin5_store(const float2* __restrict__ src,
                                               float2* __restrict__ gdst, int tid)
{
    for (int q = tid; q < 384; q += 256) {
        float2 a[5], b[5];
        #pragma unroll
        for (int u = 0; u < 5; ++u) a[u] = src[IDX(q + 384*u)];
        dft5<DIR>(a,b);
        #pragma unroll
        for (int u = 0; u < 5; ++u) gdst[q + 384*u] = b[u];
    }
}

// ---------------- kernels ----------------

// K1: row FFTs of padded h. Hrow[r][k], r=0..539 = padded row 270+r.
__global__ __launch_bounds__(256,5) void k_row_fft_h(const float* __restrict__ h,
                                                     float2* __restrict__ Hrow)
{
    __shared__ float2 bA[IDXSZ(1920)], bB[IDXSZ(1920)];
    const int tid = threadIdx.x, r = blockIdx.x;
    row_s1_fwd<false>(h + r*960, nullptr, bA, tid); __syncthreads();
    mid_stage<-1,8,240, 8>(bA, bB, tid); __syncthreads();
    mid_stage<-1,6, 30,64>(bB, bA, tid); __syncthreads();
    row_fin5_store<-1>(bA, Hrow + r*1920, tid);
}

// K2: column FFTs of Hrow (pair/thread) + build pair-interleaved KI.
// XCD-chunked swizzle: xcd = bid&7 owns columns [xcd*240, xcd*240+240).
__global__ __launch_bounds__(256,4) void k_col_fft_h_buildK(const float2* __restrict__ Hrow,
                                                            const float* __restrict__ mu1,
                                                            float4* __restrict__ KI)
{
    __shared__ float2 bA[IDXPSZ(2160)], bB[IDXPSZ(2160)];
    const int tid = threadIdx.x;
    const int xcd = blockIdx.x & 7, idx = blockIdx.x >> 3;   // idx in [0,120)
    const int cpair = xcd*120 + idx, c0 = cpair*2;
    col_s1_fwd_pair(Hrow, c0, bA, tid);  __syncthreads();
    mid_pair<-1,180, 6>(bA, bB, tid);    __syncthreads();
    mid_pair<-1, 30,36>(bB, bA, tid);    __syncthreads();
    const float sc = mu1[4] / ((1.0f + 1e-6f) * 2073600.0f);
    const float cos0 = __cosf(PI2 * (float)(c0  ) * (1.0f/1920.0f));
    const float cos1 = __cosf(PI2 * (float)(c0+1) * (1.0f/1920.0f));
    float4* Kc = KI + cpair*1080;
    for (int p = tid; p < 216; p += 256) {
        float2 a0[5],a1[5],b0[5],b1[5];
        #pragma unroll
        for (int u = 0; u < 5; ++u) ldp(bA, p + 216*u, a0[u], a1[u]);
        dft5<-1>(a0,b0); dft5<-1>(a1,b1);
        #pragma unroll
        for (int u = 0; u < 5; ++u) {
            const int k = p + 216*u;
            const float cosk = __cosf(PI2 * (float)k * (1.0f/1080.0f));
            float m0 = b0[u].x*b0[u].x + b0[u].y*b0[u].y;
            float m1 = b1[u].x*b1[u].x + b1[u].y*b1[u].y;
            float f0 = sc / (1e-6f*m0 + 1e-5f*(4.0f - 2.0f*cosk - 2.0f*cos0) + 4e-5f);
            float f1 = sc / (1e-6f*m1 + 1e-5f*(4.0f - 2.0f*cosk - 2.0f*cos1) + 4e-5f);
            Kc[k] = make_float4(f0*b0[u].x, -f0*b0[u].y, f1*b1[u].x, -f1*b1[u].y);
        }
    }
}

// K3: row FFTs of padded x, pairs packed z = x_a + i*x_b.
__global__ __launch_bounds__(256,5) void k_row_fft_x(const float* __restrict__ x,
                                                     float2* __restrict__ Z)
{
    __shared__ float2 bA[IDXSZ(1920)], bB[IDXSZ(1920)];
    const int tid = threadIdx.x;
    const int p = blockIdx.x / 540;
    const int r = blockIdx.x % 540;
    row_s1_fwd<true>(x + ((2*p)*540 + r)*960, x + ((2*p+1)*540 + r)*960, bA, tid);
    __syncthreads();
    mid_stage<-1,8,240, 8>(bA, bB, tid); __syncthreads();
    mid_stage<-1,6, 30,64>(bB, bA, tid); __syncthreads();
    row_fin5_store<-1>(bA, Z + (p*540 + r)*1920, tid);
}

// K4: fused column pass, pair-per-thread, 1 pair-plane/block, grid 3840.
// fwd (6,6,6,[5) fused K (5],6,6,6) inv; 7 passes, 6 barriers.
// XCD-chunked swizzle: xcd = bid&7, idx = bid>>3 in [0,480);
// c0 = (xcd*120 + idx%120)*2, plane = idx/120.
__global__ __launch_bounds__(256,4) void k_col_fused(float2* __restrict__ Z,
                                                     const float4* __restrict__ KI)
{
    __shared__ float2 bA[IDXPSZ(2160)], bB[IDXPSZ(2160)];
    const int tid = threadIdx.x;
    const int xcd = blockIdx.x & 7, idx = blockIdx.x >> 3;
    const int pp  = idx / 120;
    const int cpair = xcd*120 + (idx - pp*120), c0 = cpair*2;
    float2* Zp = Z + pp*540*1920;
    col_s1_fwd_pair(Zp, c0, bA, tid);      __syncthreads();
    mid_pair<-1,180, 6>(bA, bB, tid);      __syncthreads();
    mid_pair<-1, 30,36>(bB, bA, tid);      __syncthreads();
    fused5K5_pair(bA, bB, KI, cpair, tid); __syncthreads();
    mid_pair< 1,216, 5>(bB, bA, tid);      __syncthreads();
    mid_pair< 1, 36,30>(bA, bB, tid);      __syncthreads();
    fin6_crop_pair(bB, Zp, c0, tid);
}

// K5: row IFFTs + column crop remap + split pair into two real outputs.
__global__ __launch_bounds__(256,5) void k_row_ifft_out(const float2* __restrict__ Z,
                                                        float* __restrict__ out)
{
    __shared__ float2 bA[IDXSZ(1920)], bB[IDXSZ(1920)];
    const int tid = threadIdx.x;
    const int p = blockIdx.x / 540;
    const int r = blockIdx.x % 540;
    row_s1_inv(Z + (p*540 + r)*1920, bA, tid); __syncthreads();
    mid_stage<1,8,240, 8>(bA, bB, tid); __syncthreads();
    mid_stage<1,6, 30,64>(bB, bA, tid); __syncthreads();
    float* oa = out + ((2*p)*540 + r)*960;
    float* ob = out + ((2*p+1)*540 + r)*960;
    for (int q = tid; q < 384; q += 256) {
        float2 a[5], b[5];
        #pragma unroll
        for (int u = 0; u < 5; ++u) a[u] = bA[IDX(q + 384*u)];
        dft5<1>(a,b);
        oa[q+480] = b[0].x; ob[q+480] = b[0].y;
        if (q < 96)   { oa[q+864] = b[1].x; ob[q+864] = b[1].y; }
        if (q >= 288) { oa[q-288] = b[3].x; ob[q-288] = b[3].y; }
        oa[q+96]  = b[4].x; ob[q+96]  = b[4].y;
    }
}

extern "C" void kernel_launch(void* const* d_in, const int* in_sizes, int n_in,
                              void* d_out, int out_size, void* d_ws, size_t ws_size,
                              hipStream_t stream)
{
    (void)in_sizes; (void)n_in; (void)out_size; (void)ws_size;
    const float* x   = (const float*)d_in[0];
    const float* h   = (const float*)d_in[1];
    const float* mu1 = (const float*)d_in[2];
    float*       out = (float*)d_out;

    // ws layout: KI (960*1080 float4) | Z (4*540*1920 c64); Hrow aliases Z.
    float4* KI   = (float4*)d_ws;
    float2* Z    = (float2*)d_ws + 2*960*1080;
    float2* Hrow = Z;

    k_row_fft_h       <<<540,    256, 0, stream>>>(h, Hrow);
    k_col_fft_h_buildK<<<960,    256, 0, stream>>>(Hrow, mu1, KI);
    k_row_fft_x       <<<4*540,  256, 0, stream>>>(x, Z);
    k_col_fused       <<<3840,   256, 0, stream>>>(Z, KI);
    k_row_ifft_out    <<<4*540,  256, 0, stream>>>(Z, out);
}